// Round 1
// baseline (2297.086 us; speedup 1.0000x reference)
//
#include <hip/hip_runtime.h>

#define NXI 320
#define NCI 8
#define NTI 8
#define MI  65536
#define GI  640
#define G2I (GI*GI)
#define NPIX (NXI*NXI)

__device__ inline float2 cmul(float2 a, float2 b) {
    return make_float2(a.x*b.x - a.y*b.y, a.x*b.y + a.y*b.x);
}

// ---------------- gridding: scatter with folded ifftshift ----------------
__global__ __launch_bounds__(256) void grid_kernel(
    const float* __restrict__ kr, const float* __restrict__ ki,
    const float* __restrict__ traj, const float* __restrict__ dcf,
    float* __restrict__ grid, int t)
{
    int tid = blockIdx.x * 256 + threadIdx.x;   // NC*M threads, c uniform per block
    int m = tid & (MI - 1);
    int c = tid >> 16;
    float tu = traj[(m*2 + 0)*NTI + t];
    float tv = traj[(m*2 + 1)*NTI + t];
    float u = (tu + 0.5f) * (float)GI;
    float v = (tv + 0.5f) * (float)GI;
    float fu = floorf(u), fv = floorf(v);
    float du = u - fu, dv = v - fv;
    int i0 = (int)fu + GI/2; if (i0 >= GI) i0 -= GI;   // ifftshift folded in
    int j0 = (int)fv + GI/2; if (j0 >= GI) j0 -= GI;
    int i1 = i0 + 1; if (i1 >= GI) i1 -= GI;
    int j1 = j0 + 1; if (j1 >= GI) j1 -= GI;
    float w = dcf[m*NTI + t];
    float re = kr[c*MI + m] * w;
    float im = ki[c*MI + m] * w;
    float w00 = (1.f-du)*(1.f-dv), w10 = du*(1.f-dv);
    float w01 = (1.f-du)*dv,       w11 = du*dv;
    float* g = grid + (size_t)c * (2*(size_t)G2I);
    int a00 = (i0*GI + j0)*2, a10 = (i1*GI + j0)*2;
    int a01 = (i0*GI + j1)*2, a11 = (i1*GI + j1)*2;
    unsafeAtomicAdd(g + a00,     re*w00); unsafeAtomicAdd(g + a00 + 1, im*w00);
    unsafeAtomicAdd(g + a10,     re*w10); unsafeAtomicAdd(g + a10 + 1, im*w10);
    unsafeAtomicAdd(g + a01,     re*w01); unsafeAtomicAdd(g + a01 + 1, im*w01);
    unsafeAtomicAdd(g + a11,     re*w11); unsafeAtomicAdd(g + a11 + 1, im*w11);
}

// ---------------- Stockham stage, radix R, iFFT (+i twiddles) ----------------
template<int R>
__device__ inline void stage(const float2* __restrict__ x, float2* __restrict__ y,
                             int n, int s, const float2* __restrict__ W, int lane)
{
    const int m = n / R;
    const int total = m * s;
    for (int item = lane; item < total; item += 64) {
        int p = item / s;
        int q = item - p * s;
        float2 a[R];
        #pragma unroll
        for (int t = 0; t < R; ++t) a[t] = x[q + s*(p + m*t)];
        float2 b[R];
        if constexpr (R == 2) {
            b[0] = make_float2(a[0].x + a[1].x, a[0].y + a[1].y);
            b[1] = make_float2(a[0].x - a[1].x, a[0].y - a[1].y);
        } else if constexpr (R == 4) {
            float2 e0 = make_float2(a[0].x + a[2].x, a[0].y + a[2].y);
            float2 d0 = make_float2(a[0].x - a[2].x, a[0].y - a[2].y);
            float2 e1 = make_float2(a[1].x + a[3].x, a[1].y + a[3].y);
            float2 d1 = make_float2(a[1].x - a[3].x, a[1].y - a[3].y);
            b[0] = make_float2(e0.x + e1.x, e0.y + e1.y);
            b[1] = make_float2(d0.x - d1.y, d0.y + d1.x);   // d0 + i*d1
            b[2] = make_float2(e0.x - e1.x, e0.y - e1.y);
            b[3] = make_float2(d0.x + d1.y, d0.y - d1.x);   // d0 - i*d1
        } else {  // R == 5
            const float2 w5[5] = {{1.f, 0.f},
                                  { 0.309016994f,  0.951056516f},
                                  {-0.809016994f,  0.587785252f},
                                  {-0.809016994f, -0.587785252f},
                                  { 0.309016994f, -0.951056516f}};
            #pragma unroll
            for (int u = 0; u < 5; ++u) {
                float2 acc = a[0];
                #pragma unroll
                for (int t = 1; t < 5; ++t) {
                    float2 w = w5[(u*t) % 5];
                    acc.x += a[t].x*w.x - a[t].y*w.y;
                    acc.y += a[t].x*w.y + a[t].y*w.x;
                }
                b[u] = acc;
            }
        }
        #pragma unroll
        for (int u = 0; u < R; ++u) {
            int widx = p * u * s;           // provably < 640 for all stages
            float2 tw = W[widx];
            y[q + s*(R*p + u)] = cmul(b[u], tw);
        }
    }
}

// 640-pt iFFT per line; 4 lines per block (1 per wave). COL: lines are columns.
template<bool COL>
__global__ __launch_bounds__(256) void fft_pass(const float2* __restrict__ src,
                                                float2* __restrict__ dst)
{
    __shared__ float2 bufA[4][GI];
    __shared__ float2 bufB[4][GI];
    __shared__ float2 W[GI];
    const int tid = threadIdx.x;
    for (int j = tid; j < GI; j += 256) {
        float sj, cj;
        __sincosf((2.0f * 3.14159265358979f / GI) * j, &sj, &cj);
        W[j] = make_float2(cj, sj);     // e^{+2πi j / 640}
    }
    const int lid0 = blockIdx.x * 4;
    const int coil = lid0 / GI;
    const int off  = lid0 % GI;         // row0 or col0 (multiple of 4)
    if constexpr (COL) {
        const float2* sp = src + (size_t)coil * G2I + off;
        for (int idx = tid; idx < 4*GI; idx += 256) {
            int l = idx & 3, k = idx >> 2;
            bufA[l][k] = sp[(size_t)k*GI + l];
        }
    } else {
        const float2* sp = src + (size_t)coil * G2I + (size_t)off * GI;
        for (int idx = tid; idx < 4*GI; idx += 256) {
            int l = idx / GI, k = idx - l*GI;
            bufA[l][k] = sp[l*GI + k];
        }
    }
    __syncthreads();
    const int wave = tid >> 6, lane = tid & 63;
    float2* x = bufA[wave];
    float2* y = bufB[wave];
    stage<5>(x, y, 640,   1, W, lane); __syncthreads();
    stage<4>(y, x, 128,   5, W, lane); __syncthreads();
    stage<4>(x, y,  32,  20, W, lane); __syncthreads();
    stage<4>(y, x,   8,  80, W, lane); __syncthreads();
    stage<2>(x, y,   2, 320, W, lane); __syncthreads();
    // result in bufB
    if constexpr (COL) {
        float2* dp = dst + (size_t)coil * G2I + off;
        for (int idx = tid; idx < 4*GI; idx += 256) {
            int l = idx & 3, k = idx >> 2;
            dp[(size_t)k*GI + l] = bufB[l][k];
        }
    } else {
        float2* dp = dst + (size_t)coil * G2I + (size_t)off * GI;
        for (int idx = tid; idx < 4*GI; idx += 256) {
            int l = idx / GI, k = idx - l*GI;
            dp[l*GI + k] = bufB[l][k];
        }
    }
}

// ------------- crop (fftshift folded) + deapodize + coil combine -------------
__global__ __launch_bounds__(256) void combine_kernel(
    const float2* __restrict__ grid, const float* __restrict__ csr,
    const float* __restrict__ csi, float2* __restrict__ img)
{
    int idx = blockIdx.x * 256 + threadIdx.x;   // NPIX threads
    int x = idx / NXI, y = idx - x*NXI;
    int ox = x + 480; if (ox >= GI) ox -= GI;   // (160 + x + 320) % 640
    int oy = y + 480; if (oy >= GI) oy -= GI;
    const float PI = 3.14159265358979f;
    float tx = (x - 160) * (1.0f/GI);
    float ty = (y - 160) * (1.0f/GI);
    float dx = 1.0f, dy = 1.0f;
    if (x != 160) { float s = __sinf(PI*tx) / (PI*tx); dx = s*s; }
    if (y != 160) { float s = __sinf(PI*ty) / (PI*ty); dy = s*s; }
    float scale = 1.0f / ((float)G2I * dx * dy);   // ifft norm + deapod
    float accr = 0.f, acci = 0.f;
    int gbase = ox*GI + oy;
    #pragma unroll
    for (int c = 0; c < NCI; ++c) {
        float2 g = grid[(size_t)c*G2I + gbase];
        float cr = csr[c*NPIX + idx];
        float ci = csi[c*NPIX + idx];
        accr += cr*g.x + ci*g.y;     // conj(csm) * im
        acci += cr*g.y - ci*g.x;
    }
    img[idx] = make_float2(accr*scale, acci*scale);
}

// ---------------- bilinear motion warp, accumulate into out ----------------
__global__ __launch_bounds__(256) void warp_kernel(
    const float2* __restrict__ img, const float* __restrict__ motions,
    float* __restrict__ out, int t)
{
    int idx = blockIdx.x * 256 + threadIdx.x;
    int x = idx / NXI, y = idx - x*NXI;
    float fx = motions[(size_t)(idx*2 + 0)*NTI + t];
    float fy = motions[(size_t)(idx*2 + 1)*NTI + t];
    float xs = fminf(fmaxf((float)x + fx, 0.0f), (float)(NXI-1));
    float ys = fminf(fmaxf((float)y + fy, 0.0f), (float)(NXI-1));
    int x0 = (int)floorf(xs);
    int y0 = (int)floorf(ys);
    int x1 = min(x0+1, NXI-1);
    int y1 = min(y0+1, NXI-1);
    float dx = xs - (float)x0;
    float dy = ys - (float)y0;
    float2 v00 = img[x0*NXI + y0];
    float2 v10 = img[x1*NXI + y0];
    float2 v01 = img[x0*NXI + y1];
    float2 v11 = img[x1*NXI + y1];
    float w00 = (1.f-dx)*(1.f-dy), w10 = dx*(1.f-dy);
    float w01 = (1.f-dx)*dy,       w11 = dx*dy;
    out[idx*2+0] += w00*v00.x + w10*v10.x + w01*v01.x + w11*v11.x;
    out[idx*2+1] += w00*v00.y + w10*v10.y + w01*v01.y + w11*v11.y;
}

extern "C" void kernel_launch(void* const* d_in, const int* in_sizes, int n_in,
                              void* d_out, int out_size, void* d_ws, size_t ws_size,
                              hipStream_t stream)
{
    const float* kr   = (const float*)d_in[0];
    const float* ki   = (const float*)d_in[1];
    const float* traj = (const float*)d_in[2];
    const float* csr  = (const float*)d_in[3];
    const float* csi  = (const float*)d_in[4];
    const float* dcf  = (const float*)d_in[5];
    const float* mot  = (const float*)d_in[6];
    float* out = (float*)d_out;

    char* ws = (char*)d_ws;
    const size_t gbytes = (size_t)NCI * G2I * sizeof(float2);   // 26,214,400 B
    float2* gridA = (float2*)ws;
    float2* gridB = (float2*)(ws + gbytes);
    float2* img   = (float2*)(ws + 2*gbytes);

    hipMemsetAsync(d_out, 0, (size_t)out_size * sizeof(float), stream);

    for (int t = 0; t < NTI; ++t) {
        hipMemsetAsync(gridA, 0, gbytes, stream);
        grid_kernel<<<NCI*MI/256, 256, 0, stream>>>(kr, ki, traj, dcf, (float*)gridA, t);
        fft_pass<false><<<NCI*GI/4, 256, 0, stream>>>(gridA, gridB);   // rows
        fft_pass<true ><<<NCI*GI/4, 256, 0, stream>>>(gridB, gridA);   // cols
        combine_kernel<<<NPIX/256, 256, 0, stream>>>(gridA, csr, csi, img);
        warp_kernel<<<NPIX/256, 256, 0, stream>>>(img, mot, out, t);
    }
}

// Round 2
// 889.646 us; speedup vs baseline: 2.5820x; 2.5820x over previous
//
#include <hip/hip_runtime.h>

#define NXI 320
#define NCI 8
#define NTI 8
#define MI  65536
#define GI  640
#define G2I (GI*GI)
#define NPIX (NXI*NXI)
#define NBLK 1600          // G2I / 256

__device__ inline float2 cmul(float2 a, float2 b) {
    return make_float2(a.x*b.x - a.y*b.y, a.x*b.y + a.y*b.x);
}

__device__ inline void cell_of(const float* __restrict__ traj, int m, int t,
                               int& i0s, int& j0s, float& du, float& dv)
{
    float tu = traj[(m*2 + 0)*NTI + t];
    float tv = traj[(m*2 + 1)*NTI + t];
    float u = (tu + 0.5f) * (float)GI;
    float v = (tv + 0.5f) * (float)GI;
    float fu = floorf(u), fv = floorf(v);
    du = u - fu; dv = v - fv;
    i0s = (int)fu + GI/2; if (i0s >= GI) i0s -= GI;   // ifftshift folded in
    j0s = (int)fv + GI/2; if (j0s >= GI) j0s -= GI;
}

// ---------------- binning: count ----------------
__global__ __launch_bounds__(256) void count_kernel(
    const float* __restrict__ traj, int* __restrict__ counts, int t)
{
    int m = blockIdx.x * 256 + threadIdx.x;
    int i0s, j0s; float du, dv;
    cell_of(traj, m, t, i0s, j0s, du, dv);
    atomicAdd(&counts[i0s*GI + j0s], 1);
}

// ---------------- scan (exclusive) over G2I = 1600 x 256 ----------------
__device__ inline int block_incl_scan(int v, int tid, int* tmp) {
    tmp[tid] = v; __syncthreads();
    for (int d = 1; d < 256; d <<= 1) {
        int y = (tid >= d) ? tmp[tid - d] : 0;
        __syncthreads();
        tmp[tid] += y;
        __syncthreads();
    }
    return tmp[tid];
}

__global__ __launch_bounds__(256) void scanA(const int* __restrict__ counts,
                                             int* __restrict__ offs,
                                             int* __restrict__ sums)
{
    __shared__ int tmp[256];
    int tid = threadIdx.x;
    int i = blockIdx.x * 256 + tid;
    int v = counts[i];
    int incl = block_incl_scan(v, tid, tmp);
    offs[i] = incl - v;                       // local exclusive
    if (tid == 255) sums[blockIdx.x] = incl;  // block total
}

__global__ __launch_bounds__(256) void scanB(int* __restrict__ sums)
{
    __shared__ int tmp[256];
    __shared__ int carry;
    int tid = threadIdx.x;
    if (tid == 0) carry = 0;
    __syncthreads();
    for (int c = 0; c < NBLK; c += 256) {
        int i = c + tid;
        int v = (i < NBLK) ? sums[i] : 0;
        int incl = block_incl_scan(v, tid, tmp);
        int tot = tmp[255];
        if (i < NBLK) sums[i] = carry + incl - v;
        __syncthreads();
        if (tid == 0) carry += tot;
        __syncthreads();
    }
}

__global__ __launch_bounds__(256) void scanC(int* __restrict__ offs,
                                             const int* __restrict__ sums)
{
    int i = blockIdx.x * 256 + threadIdx.x;
    offs[i] += sums[blockIdx.x];
}

// ---------------- scatter samples into bin-sorted records ----------------
// record: {du, dv, (re,im) x 8 coils, pre-weighted by dcf} = 18 floats
__global__ __launch_bounds__(256) void scatter_kernel(
    const float* __restrict__ kr, const float* __restrict__ ki,
    const float* __restrict__ traj, const float* __restrict__ dcf,
    int* __restrict__ offs, float* __restrict__ recs, int t)
{
    int m = blockIdx.x * 256 + threadIdx.x;
    int i0s, j0s; float du, dv;
    cell_of(traj, m, t, i0s, j0s, du, dv);
    float w = dcf[m*NTI + t];
    int slot = atomicAdd(&offs[i0s*GI + j0s], 1);
    float* r = recs + (size_t)slot * 18;
    r[0] = du; r[1] = dv;
    #pragma unroll
    for (int c = 0; c < NCI; ++c) {
        r[2 + 2*c] = kr[c*MI + m] * w;
        r[3 + 2*c] = ki[c*MI + m] * w;
    }
}

// ---------------- gather: one thread per grid cell, all 8 coils ----------------
// after scatter, offs[bin] == end of bin's range; start = end - counts[bin]
__global__ __launch_bounds__(256) void gather_kernel(
    const int* __restrict__ counts, const int* __restrict__ offs,
    const float* __restrict__ recs, float2* __restrict__ grid)
{
    int idx = blockIdx.x * 256 + threadIdx.x;   // G2I threads
    int i = idx / GI, j = idx - i*GI;
    int im1 = i ? i - 1 : GI - 1;
    int jm1 = j ? j - 1 : GI - 1;
    int rows[2] = {im1, i};
    int cols[2] = {jm1, j};
    float2 acc[NCI];
    #pragma unroll
    for (int c = 0; c < NCI; ++c) acc[c] = make_float2(0.f, 0.f);
    #pragma unroll
    for (int a = 0; a < 2; ++a) {
        #pragma unroll
        for (int b = 0; b < 2; ++b) {
            int bin = rows[a]*GI + cols[b];
            int end = offs[bin];
            int cnt = counts[bin];
            for (int s = end - cnt; s < end; ++s) {
                const float* r = recs + (size_t)s * 18;
                float du = r[0], dv = r[1];
                float fx = a ? (1.f - du) : du;   // row i  -> sample i0 -> (1-du); row i-1 -> via i0+1 -> du
                float fy = b ? (1.f - dv) : dv;
                float wgt = fx * fy;
                #pragma unroll
                for (int c = 0; c < NCI; ++c) {
                    acc[c].x += wgt * r[2 + 2*c];
                    acc[c].y += wgt * r[3 + 2*c];
                }
            }
        }
    }
    #pragma unroll
    for (int c = 0; c < NCI; ++c)
        grid[(size_t)c * G2I + idx] = acc[c];
}

// ---------------- Stockham stage, radix R, iFFT (+i twiddles) ----------------
template<int R>
__device__ inline void stage(const float2* __restrict__ x, float2* __restrict__ y,
                             int n, int s, const float2* __restrict__ W, int lane)
{
    const int m = n / R;
    const int total = m * s;
    for (int item = lane; item < total; item += 64) {
        int p = item / s;
        int q = item - p * s;
        float2 a[R];
        #pragma unroll
        for (int t = 0; t < R; ++t) a[t] = x[q + s*(p + m*t)];
        float2 b[R];
        if constexpr (R == 2) {
            b[0] = make_float2(a[0].x + a[1].x, a[0].y + a[1].y);
            b[1] = make_float2(a[0].x - a[1].x, a[0].y - a[1].y);
        } else if constexpr (R == 4) {
            float2 e0 = make_float2(a[0].x + a[2].x, a[0].y + a[2].y);
            float2 d0 = make_float2(a[0].x - a[2].x, a[0].y - a[2].y);
            float2 e1 = make_float2(a[1].x + a[3].x, a[1].y + a[3].y);
            float2 d1 = make_float2(a[1].x - a[3].x, a[1].y - a[3].y);
            b[0] = make_float2(e0.x + e1.x, e0.y + e1.y);
            b[1] = make_float2(d0.x - d1.y, d0.y + d1.x);   // d0 + i*d1
            b[2] = make_float2(e0.x - e1.x, e0.y - e1.y);
            b[3] = make_float2(d0.x + d1.y, d0.y - d1.x);   // d0 - i*d1
        } else {  // R == 5
            const float2 w5[5] = {{1.f, 0.f},
                                  { 0.309016994f,  0.951056516f},
                                  {-0.809016994f,  0.587785252f},
                                  {-0.809016994f, -0.587785252f},
                                  { 0.309016994f, -0.951056516f}};
            #pragma unroll
            for (int u = 0; u < 5; ++u) {
                float2 acc = a[0];
                #pragma unroll
                for (int t = 1; t < 5; ++t) {
                    float2 w = w5[(u*t) % 5];
                    acc.x += a[t].x*w.x - a[t].y*w.y;
                    acc.y += a[t].x*w.y + a[t].y*w.x;
                }
                b[u] = acc;
            }
        }
        #pragma unroll
        for (int u = 0; u < R; ++u) {
            int widx = p * u * s;           // provably < 640 for all stages
            float2 tw = W[widx];
            y[q + s*(R*p + u)] = cmul(b[u], tw);
        }
    }
}

// 640-pt iFFT per line; 4 lines per block (1 per wave). COL: lines are columns.
template<bool COL>
__global__ __launch_bounds__(256) void fft_pass(const float2* __restrict__ src,
                                                float2* __restrict__ dst)
{
    __shared__ float2 bufA[4][GI];
    __shared__ float2 bufB[4][GI];
    __shared__ float2 W[GI];
    const int tid = threadIdx.x;
    for (int j = tid; j < GI; j += 256) {
        float sj, cj;
        __sincosf((2.0f * 3.14159265358979f / GI) * j, &sj, &cj);
        W[j] = make_float2(cj, sj);     // e^{+2πi j / 640}
    }
    const int lid0 = blockIdx.x * 4;
    const int coil = lid0 / GI;
    const int off  = lid0 % GI;         // row0 or col0 (multiple of 4)
    if constexpr (COL) {
        const float2* sp = src + (size_t)coil * G2I + off;
        for (int idx = tid; idx < 4*GI; idx += 256) {
            int l = idx & 3, k = idx >> 2;
            bufA[l][k] = sp[(size_t)k*GI + l];
        }
    } else {
        const float2* sp = src + (size_t)coil * G2I + (size_t)off * GI;
        for (int idx = tid; idx < 4*GI; idx += 256) {
            int l = idx / GI, k = idx - l*GI;
            bufA[l][k] = sp[l*GI + k];
        }
    }
    __syncthreads();
    const int wave = tid >> 6, lane = tid & 63;
    float2* x = bufA[wave];
    float2* y = bufB[wave];
    stage<5>(x, y, 640,   1, W, lane); __syncthreads();
    stage<4>(y, x, 128,   5, W, lane); __syncthreads();
    stage<4>(x, y,  32,  20, W, lane); __syncthreads();
    stage<4>(y, x,   8,  80, W, lane); __syncthreads();
    stage<2>(x, y,   2, 320, W, lane); __syncthreads();
    // result in bufB
    if constexpr (COL) {
        float2* dp = dst + (size_t)coil * G2I + off;
        for (int idx = tid; idx < 4*GI; idx += 256) {
            int l = idx & 3, k = idx >> 2;
            dp[(size_t)k*GI + l] = bufB[l][k];
        }
    } else {
        float2* dp = dst + (size_t)coil * G2I + (size_t)off * GI;
        for (int idx = tid; idx < 4*GI; idx += 256) {
            int l = idx / GI, k = idx - l*GI;
            dp[l*GI + k] = bufB[l][k];
        }
    }
}

// ------------- crop (fftshift folded) + deapodize + coil combine -------------
__global__ __launch_bounds__(256) void combine_kernel(
    const float2* __restrict__ grid, const float* __restrict__ csr,
    const float* __restrict__ csi, float2* __restrict__ img)
{
    int idx = blockIdx.x * 256 + threadIdx.x;   // NPIX threads
    int x = idx / NXI, y = idx - x*NXI;
    int ox = x + 480; if (ox >= GI) ox -= GI;   // (160 + x + 320) % 640
    int oy = y + 480; if (oy >= GI) oy -= GI;
    const float PI = 3.14159265358979f;
    float tx = (x - 160) * (1.0f/GI);
    float ty = (y - 160) * (1.0f/GI);
    float dx = 1.0f, dy = 1.0f;
    if (x != 160) { float s = __sinf(PI*tx) / (PI*tx); dx = s*s; }
    if (y != 160) { float s = __sinf(PI*ty) / (PI*ty); dy = s*s; }
    float scale = 1.0f / ((float)G2I * dx * dy);   // ifft norm + deapod
    float accr = 0.f, acci = 0.f;
    int gbase = ox*GI + oy;
    #pragma unroll
    for (int c = 0; c < NCI; ++c) {
        float2 g = grid[(size_t)c*G2I + gbase];
        float cr = csr[c*NPIX + idx];
        float ci = csi[c*NPIX + idx];
        accr += cr*g.x + ci*g.y;     // conj(csm) * im
        acci += cr*g.y - ci*g.x;
    }
    img[idx] = make_float2(accr*scale, acci*scale);
}

// ---------------- bilinear motion warp, accumulate into out ----------------
__global__ __launch_bounds__(256) void warp_kernel(
    const float2* __restrict__ img, const float* __restrict__ motions,
    float* __restrict__ out, int t)
{
    int idx = blockIdx.x * 256 + threadIdx.x;
    int x = idx / NXI, y = idx - x*NXI;
    float fx = motions[(size_t)(idx*2 + 0)*NTI + t];
    float fy = motions[(size_t)(idx*2 + 1)*NTI + t];
    float xs = fminf(fmaxf((float)x + fx, 0.0f), (float)(NXI-1));
    float ys = fminf(fmaxf((float)y + fy, 0.0f), (float)(NXI-1));
    int x0 = (int)floorf(xs);
    int y0 = (int)floorf(ys);
    int x1 = min(x0+1, NXI-1);
    int y1 = min(y0+1, NXI-1);
    float dx = xs - (float)x0;
    float dy = ys - (float)y0;
    float2 v00 = img[x0*NXI + y0];
    float2 v10 = img[x1*NXI + y0];
    float2 v01 = img[x0*NXI + y1];
    float2 v11 = img[x1*NXI + y1];
    float w00 = (1.f-dx)*(1.f-dy), w10 = dx*(1.f-dy);
    float w01 = (1.f-dx)*dy,       w11 = dx*dy;
    out[idx*2+0] += w00*v00.x + w10*v10.x + w01*v01.x + w11*v11.x;
    out[idx*2+1] += w00*v00.y + w10*v10.y + w01*v01.y + w11*v11.y;
}

extern "C" void kernel_launch(void* const* d_in, const int* in_sizes, int n_in,
                              void* d_out, int out_size, void* d_ws, size_t ws_size,
                              hipStream_t stream)
{
    const float* kr   = (const float*)d_in[0];
    const float* ki   = (const float*)d_in[1];
    const float* traj = (const float*)d_in[2];
    const float* csr  = (const float*)d_in[3];
    const float* csi  = (const float*)d_in[4];
    const float* dcf  = (const float*)d_in[5];
    const float* mot  = (const float*)d_in[6];
    float* out = (float*)d_out;

    char* ws = (char*)d_ws;
    const size_t gbytes = (size_t)NCI * G2I * sizeof(float2);   // 26,214,400 B
    float2* gridA  = (float2*)ws;                 ws += gbytes;
    float2* gridB  = (float2*)ws;                 ws += gbytes;
    float2* img    = (float2*)ws;                 ws += (size_t)NPIX * sizeof(float2);
    int*    counts = (int*)ws;                    ws += (size_t)G2I * sizeof(int);
    int*    offs   = (int*)ws;                    ws += (size_t)G2I * sizeof(int);
    int*    sums   = (int*)ws;                    ws += 64 * 1024;
    float*  recs   = (float*)ws;                  // 65536 * 72 B = 4.7 MB

    hipMemsetAsync(d_out, 0, (size_t)out_size * sizeof(float), stream);

    for (int t = 0; t < NTI; ++t) {
        hipMemsetAsync(counts, 0, (size_t)G2I * sizeof(int), stream);
        count_kernel  <<<MI/256, 256, 0, stream>>>(traj, counts, t);
        scanA         <<<NBLK,   256, 0, stream>>>(counts, offs, sums);
        scanB         <<<1,      256, 0, stream>>>(sums);
        scanC         <<<NBLK,   256, 0, stream>>>(offs, sums);
        scatter_kernel<<<MI/256, 256, 0, stream>>>(kr, ki, traj, dcf, offs, recs, t);
        gather_kernel <<<NBLK,   256, 0, stream>>>(counts, offs, recs, gridA);
        fft_pass<false><<<NCI*GI/4, 256, 0, stream>>>(gridA, gridB);   // rows
        fft_pass<true ><<<NCI*GI/4, 256, 0, stream>>>(gridB, gridA);   // cols
        combine_kernel<<<NPIX/256, 256, 0, stream>>>(gridA, csr, csi, img);
        warp_kernel   <<<NPIX/256, 256, 0, stream>>>(img, mot, out, t);
    }
}

// Round 3
// 560.042 us; speedup vs baseline: 4.1016x; 1.5885x over previous
//
#include <hip/hip_runtime.h>

#define NXI 320
#define NCI 8
#define NTI 8
#define MI  65536
#define GI  640
#define G2I (GI*GI)
#define NPIX (NXI*NXI)
#define REC_F 20     // floats per record: {j0,du,dv,pad, 8x(re,im)}

__device__ inline float2 cmul(float2 a, float2 b) {
    return make_float2(a.x*b.x - a.y*b.y, a.x*b.y + a.y*b.x);
}

__device__ inline void cell_of(const float* __restrict__ traj, int m, int f,
                               int& i0s, int& j0s, float& du, float& dv)
{
    float tu = traj[(m*2 + 0)*NTI + f];
    float tv = traj[(m*2 + 1)*NTI + f];
    float u = (tu + 0.5f) * (float)GI;
    float v = (tv + 0.5f) * (float)GI;
    float fu = floorf(u), fv = floorf(v);
    du = u - fu; dv = v - fv;
    i0s = (int)fu + GI/2; if (i0s >= GI) i0s -= GI;   // ifftshift folded in
    j0s = (int)fv + GI/2; if (j0s >= GI) j0s -= GI;
}

// ---------------- binning by grid ROW, all frames batched ----------------
__global__ __launch_bounds__(256) void count_rows(
    const float* __restrict__ traj, int* __restrict__ rowcnt)
{
    int tid = blockIdx.x * 256 + threadIdx.x;   // f*MI + m
    int f = tid >> 16, m = tid & (MI - 1);
    int i0s, j0s; float du, dv;
    cell_of(traj, m, f, i0s, j0s, du, dv);
    atomicAdd(&rowcnt[f*GI + i0s], 1);
}

__device__ inline int block_incl_scan(int v, int tid, int* tmp) {
    tmp[tid] = v; __syncthreads();
    for (int d = 1; d < 256; d <<= 1) {
        int y = (tid >= d) ? tmp[tid - d] : 0;
        __syncthreads();
        tmp[tid] += y;
        __syncthreads();
    }
    return tmp[tid];
}

// one block per frame: exclusive scan of 640 row counts -> rowstart & rowoff
__global__ __launch_bounds__(256) void scan_rows(
    const int* __restrict__ rowcnt, int* __restrict__ rowstart,
    int* __restrict__ rowoff)
{
    __shared__ int tmp[256];
    __shared__ int carry;
    int f = blockIdx.x, tid = threadIdx.x;
    if (tid == 0) carry = 0;
    __syncthreads();
    for (int c = 0; c < GI; c += 256) {
        int i = c + tid;
        int v = (i < GI) ? rowcnt[f*GI + i] : 0;
        int incl = block_incl_scan(v, tid, tmp);
        int excl = carry + incl - v;
        if (i < GI) { rowstart[f*(GI+1) + i] = excl; rowoff[f*GI + i] = excl; }
        int tot = tmp[255];
        __syncthreads();
        if (tid == 0) carry += tot;
        __syncthreads();
    }
    if (tid == 0) rowstart[f*(GI+1) + GI] = MI;
}

// scatter samples into row-sorted records (dcf pre-applied)
__global__ __launch_bounds__(256) void scatter_rows(
    const float* __restrict__ kr, const float* __restrict__ ki,
    const float* __restrict__ traj, const float* __restrict__ dcf,
    int* __restrict__ rowoff, float* __restrict__ recs)
{
    int tid = blockIdx.x * 256 + threadIdx.x;   // f*MI + m
    int f = tid >> 16, m = tid & (MI - 1);
    int i0s, j0s; float du, dv;
    cell_of(traj, m, f, i0s, j0s, du, dv);
    float w = dcf[m*NTI + f];
    int slot = atomicAdd(&rowoff[f*GI + i0s], 1);
    float4* r = (float4*)(recs + ((size_t)f*MI + slot) * REC_F);
    r[0] = make_float4(__int_as_float(j0s), du, dv, 0.f);
    #pragma unroll
    for (int q = 0; q < 4; ++q) {
        int c0 = 2*q;
        r[1+q] = make_float4(kr[c0*MI + m]*w,     ki[c0*MI + m]*w,
                             kr[(c0+1)*MI + m]*w, ki[(c0+1)*MI + m]*w);
    }
}

// ---------------- Stockham stage, radix R, iFFT (+i twiddles) ----------------
template<int R>
__device__ inline void stage(const float2* __restrict__ x, float2* __restrict__ y,
                             int n, int s, const float2* __restrict__ W, int lane)
{
    const int m = n / R;
    const int total = m * s;
    for (int item = lane; item < total; item += 64) {
        int p = item / s;
        int q = item - p * s;
        float2 a[R];
        #pragma unroll
        for (int t = 0; t < R; ++t) a[t] = x[q + s*(p + m*t)];
        float2 b[R];
        if constexpr (R == 2) {
            b[0] = make_float2(a[0].x + a[1].x, a[0].y + a[1].y);
            b[1] = make_float2(a[0].x - a[1].x, a[0].y - a[1].y);
        } else if constexpr (R == 4) {
            float2 e0 = make_float2(a[0].x + a[2].x, a[0].y + a[2].y);
            float2 d0 = make_float2(a[0].x - a[2].x, a[0].y - a[2].y);
            float2 e1 = make_float2(a[1].x + a[3].x, a[1].y + a[3].y);
            float2 d1 = make_float2(a[1].x - a[3].x, a[1].y - a[3].y);
            b[0] = make_float2(e0.x + e1.x, e0.y + e1.y);
            b[1] = make_float2(d0.x - d1.y, d0.y + d1.x);
            b[2] = make_float2(e0.x - e1.x, e0.y - e1.y);
            b[3] = make_float2(d0.x + d1.y, d0.y - d1.x);
        } else {  // R == 5
            const float2 w5[5] = {{1.f, 0.f},
                                  { 0.309016994f,  0.951056516f},
                                  {-0.809016994f,  0.587785252f},
                                  {-0.809016994f, -0.587785252f},
                                  { 0.309016994f, -0.951056516f}};
            #pragma unroll
            for (int u = 0; u < 5; ++u) {
                float2 acc = a[0];
                #pragma unroll
                for (int t = 1; t < 5; ++t) {
                    float2 w = w5[(u*t) % 5];
                    acc.x += a[t].x*w.x - a[t].y*w.y;
                    acc.y += a[t].x*w.y + a[t].y*w.x;
                }
                b[u] = acc;
            }
        }
        #pragma unroll
        for (int u = 0; u < R; ++u) {
            float2 tw = W[p * u * s];
            y[q + s*(R*p + u)] = cmul(b[u], tw);
        }
    }
}

__device__ inline void fill_W(float2* W, int tid, int nthr) {
    for (int j = tid; j < GI; j += nthr) {
        float sj, cj;
        __sincosf((2.0f * 3.14159265358979f / GI) * j, &sj, &cj);
        W[j] = make_float2(cj, sj);     // e^{+2 pi i j / 640}
    }
}

// ---- fused gather + row FFT: block = (frame, grid-row i, coil-half h) ----
// gathers 4 coils' row data from records into LDS, FFTs along j (640 pts),
// writes only the 320 cropped columns: rowout[f][c][i][yc] with
// yc -> actual j = (yc+480)%640 folded in.
__global__ __launch_bounds__(256) void row_fft(
    const int* __restrict__ rowstart, const float* __restrict__ recs,
    float2* __restrict__ rowout)
{
    __shared__ float2 A[4][GI];
    __shared__ float2 B[4][GI];
    __shared__ float2 W[GI];
    int bid = blockIdx.x;               // ((f*640)+i)*2 + h
    int h = bid & 1;
    int i = (bid >> 1) % GI;
    int f = bid / (2*GI);
    int tid = threadIdx.x;
    fill_W(W, tid, 256);
    for (int idx = tid; idx < 4*GI; idx += 256)
        A[idx / GI][idx - (idx/GI)*GI] = make_float2(0.f, 0.f);
    __syncthreads();

    // gather: part 0 = bin-row i (weight 1-du), part 1 = bin-row i-1 (weight du)
    #pragma unroll
    for (int part = 0; part < 2; ++part) {
        int r = i - part; if (r < 0) r += GI;
        int s0 = rowstart[f*(GI+1) + r];
        int s1 = rowstart[f*(GI+1) + r + 1];
        for (int s = s0 + tid; s < s1; s += 256) {
            const float4* rec = (const float4*)(recs + ((size_t)f*MI + s) * REC_F);
            float4 hd = rec[0];
            float4 d0 = rec[1 + 2*h];
            float4 d1 = rec[2 + 2*h];
            int j0 = __float_as_int(hd.x);
            float du = hd.y, dv = hd.z;
            int j1 = j0 + 1; if (j1 >= GI) j1 -= GI;
            float wr = part ? du : (1.f - du);
            float w0 = wr * (1.f - dv), w1 = wr * dv;
            atomicAdd(&A[0][j0].x, w0*d0.x); atomicAdd(&A[0][j0].y, w0*d0.y);
            atomicAdd(&A[0][j1].x, w1*d0.x); atomicAdd(&A[0][j1].y, w1*d0.y);
            atomicAdd(&A[1][j0].x, w0*d0.z); atomicAdd(&A[1][j0].y, w0*d0.w);
            atomicAdd(&A[1][j1].x, w1*d0.z); atomicAdd(&A[1][j1].y, w1*d0.w);
            atomicAdd(&A[2][j0].x, w0*d1.x); atomicAdd(&A[2][j0].y, w0*d1.y);
            atomicAdd(&A[2][j1].x, w1*d1.x); atomicAdd(&A[2][j1].y, w1*d1.y);
            atomicAdd(&A[3][j0].x, w0*d1.z); atomicAdd(&A[3][j0].y, w0*d1.w);
            atomicAdd(&A[3][j1].x, w1*d1.z); atomicAdd(&A[3][j1].y, w1*d1.w);
        }
    }
    __syncthreads();

    int wv = tid >> 6, lane = tid & 63;   // 4 waves, one line each
    float2* x = A[wv];
    float2* y = B[wv];
    stage<5>(x, y, 640,   1, W, lane); __syncthreads();
    stage<4>(y, x, 128,   5, W, lane); __syncthreads();
    stage<4>(x, y,  32,  20, W, lane); __syncthreads();
    stage<4>(y, x,   8,  80, W, lane); __syncthreads();
    stage<2>(x, y,   2, 320, W, lane); __syncthreads();
    // result in B; write cropped columns
    for (int idx = tid; idx < 4*NXI; idx += 256) {
        int cl = idx / NXI, yc = idx - cl*NXI;
        int j = yc + 480; if (j >= GI) j -= GI;
        int coil = 4*h + cl;
        rowout[(((size_t)f*NCI + coil)*GI + i)*NXI + yc] = B[cl][j];
    }
}

// ---- col FFT + crop: block = (frame, coil, y-group of 4) ----
// transforms along i (640 pts) for 4 adjacent y's, writes only the 320
// cropped rows: colimg[f][c][x][y], x -> actual i = (x+480)%640 folded in.
__global__ __launch_bounds__(256) void col_fft(
    const float2* __restrict__ rowout, float2* __restrict__ colimg)
{
    __shared__ float2 A[4][GI];
    __shared__ float2 B[4][GI];
    __shared__ float2 W[GI];
    int bid = blockIdx.x;               // (f*8 + c)*80 + g
    int g = bid % 80;
    int c = (bid / 80) % NCI;
    int f = bid / (80*NCI);
    int y0 = g * 4;
    int tid = threadIdx.x;
    fill_W(W, tid, 256);
    const float2* src = rowout + ((size_t)f*NCI + c)*GI*NXI + y0;
    for (int idx = tid; idx < 4*GI; idx += 256) {
        int l = idx & 3, k = idx >> 2;
        A[l][k] = src[(size_t)k*NXI + l];
    }
    __syncthreads();
    int wv = tid >> 6, lane = tid & 63;
    float2* x = A[wv];
    float2* y = B[wv];
    stage<5>(x, y, 640,   1, W, lane); __syncthreads();
    stage<4>(y, x, 128,   5, W, lane); __syncthreads();
    stage<4>(x, y,  32,  20, W, lane); __syncthreads();
    stage<4>(y, x,   8,  80, W, lane); __syncthreads();
    stage<2>(x, y,   2, 320, W, lane); __syncthreads();
    float2* dst = colimg + ((size_t)f*NCI + c)*NPIX + y0;
    for (int idx = tid; idx < 4*NXI; idx += 256) {
        int l = idx & 3, xx = idx >> 2;
        int j = xx + 480; if (j >= GI) j -= GI;
        dst[(size_t)xx*NXI + l] = B[l][j];
    }
}

// ------------- deapodize + coil combine (crop already folded in) -------------
__global__ __launch_bounds__(256) void combine_kernel(
    const float2* __restrict__ colimg, const float* __restrict__ csr,
    const float* __restrict__ csi, float2* __restrict__ img)
{
    int f = blockIdx.y;
    int pix = blockIdx.x * 256 + threadIdx.x;
    int x = pix / NXI, y = pix - x*NXI;
    const float PI = 3.14159265358979f;
    float tx = (x - 160) * (1.0f/GI);
    float ty = (y - 160) * (1.0f/GI);
    float dx = 1.0f, dy = 1.0f;
    if (x != 160) { float s = __sinf(PI*tx) / (PI*tx); dx = s*s; }
    if (y != 160) { float s = __sinf(PI*ty) / (PI*ty); dy = s*s; }
    float scale = 1.0f / ((float)G2I * dx * dy);
    float accr = 0.f, acci = 0.f;
    #pragma unroll
    for (int c = 0; c < NCI; ++c) {
        float2 g = colimg[((size_t)f*NCI + c)*NPIX + pix];
        float cr = csr[c*NPIX + pix];
        float ci = csi[c*NPIX + pix];
        accr += cr*g.x + ci*g.y;
        acci += cr*g.y - ci*g.x;
    }
    img[(size_t)f*NPIX + pix] = make_float2(accr*scale, acci*scale);
}

// ---------------- warp all frames + sum, write out directly ----------------
__global__ __launch_bounds__(256) void warp_sum(
    const float2* __restrict__ img, const float* __restrict__ motions,
    float* __restrict__ out)
{
    int pix = blockIdx.x * 256 + threadIdx.x;
    int x = pix / NXI, y = pix - x*NXI;
    float accr = 0.f, acci = 0.f;
    #pragma unroll
    for (int f = 0; f < NTI; ++f) {
        float fx = motions[(size_t)(pix*2 + 0)*NTI + f];
        float fy = motions[(size_t)(pix*2 + 1)*NTI + f];
        float xs = fminf(fmaxf((float)x + fx, 0.0f), (float)(NXI-1));
        float ys = fminf(fmaxf((float)y + fy, 0.0f), (float)(NXI-1));
        int x0 = (int)floorf(xs);
        int y0 = (int)floorf(ys);
        int x1 = min(x0+1, NXI-1);
        int y1 = min(y0+1, NXI-1);
        float dx = xs - (float)x0;
        float dy = ys - (float)y0;
        const float2* im = img + (size_t)f*NPIX;
        float2 v00 = im[x0*NXI + y0];
        float2 v10 = im[x1*NXI + y0];
        float2 v01 = im[x0*NXI + y1];
        float2 v11 = im[x1*NXI + y1];
        float w00 = (1.f-dx)*(1.f-dy), w10 = dx*(1.f-dy);
        float w01 = (1.f-dx)*dy,       w11 = dx*dy;
        accr += w00*v00.x + w10*v10.x + w01*v01.x + w11*v11.x;
        acci += w00*v00.y + w10*v10.y + w01*v01.y + w11*v11.y;
    }
    out[pix*2+0] = accr;
    out[pix*2+1] = acci;
}

extern "C" void kernel_launch(void* const* d_in, const int* in_sizes, int n_in,
                              void* d_out, int out_size, void* d_ws, size_t ws_size,
                              hipStream_t stream)
{
    const float* kr   = (const float*)d_in[0];
    const float* ki   = (const float*)d_in[1];
    const float* traj = (const float*)d_in[2];
    const float* csr  = (const float*)d_in[3];
    const float* csi  = (const float*)d_in[4];
    const float* dcf  = (const float*)d_in[5];
    const float* mot  = (const float*)d_in[6];
    float* out = (float*)d_out;

    char* ws = (char*)d_ws;
    float*  recs     = (float*)ws;                       // 8*65536*80 B = 41.94 MB
    ws += (size_t)NTI * MI * REC_F * sizeof(float);
    float2* rowout   = (float2*)ws;                      // 8*8*640*320*8 = 104.86 MB
    ws += (size_t)NTI * NCI * GI * NXI * sizeof(float2);
    float2* colimg   = (float2*)ws;                      // 8*8*320*320*8 = 52.43 MB
    ws += (size_t)NTI * NCI * NPIX * sizeof(float2);
    float2* img      = (float2*)ws;                      // 8*320*320*8 = 6.55 MB
    ws += (size_t)NTI * NPIX * sizeof(float2);
    int*    rowcnt   = (int*)ws;  ws += (size_t)NTI * GI * sizeof(int);
    int*    rowstart = (int*)ws;  ws += (size_t)NTI * (GI+1) * sizeof(int) + 64;
    int*    rowoff   = (int*)ws;  ws += (size_t)NTI * GI * sizeof(int);

    hipMemsetAsync(rowcnt, 0, (size_t)NTI * GI * sizeof(int), stream);
    count_rows  <<<NTI*MI/256, 256, 0, stream>>>(traj, rowcnt);
    scan_rows   <<<NTI,        256, 0, stream>>>(rowcnt, rowstart, rowoff);
    scatter_rows<<<NTI*MI/256, 256, 0, stream>>>(kr, ki, traj, dcf, rowoff, recs);
    row_fft     <<<NTI*GI*2,   256, 0, stream>>>(rowstart, recs, rowout);
    col_fft     <<<NTI*NCI*80, 256, 0, stream>>>(rowout, colimg);
    combine_kernel<<<dim3(NPIX/256, NTI), 256, 0, stream>>>(colimg, csr, csi, img);
    warp_sum    <<<NPIX/256,   256, 0, stream>>>(img, mot, out);
}

// Round 4
// 550.540 us; speedup vs baseline: 4.1724x; 1.0173x over previous
//
#include <hip/hip_runtime.h>

#define NXI 320
#define NCI 8
#define NTI 8
#define MI  65536
#define GI  640
#define G2I (GI*GI)
#define NPIX (NXI*NXI)
#define REC_F 20     // floats per record: {j0,du,dv,pad, 8x(re,im)}
#define SP 642       // padded LDS line stride (float2) — distinct banks per coil

__device__ inline float2 cmul(float2 a, float2 b) {
    return make_float2(a.x*b.x - a.y*b.y, a.x*b.y + a.y*b.x);
}

__device__ inline void cell_of(const float* __restrict__ traj, int m, int f,
                               int& i0s, int& j0s, float& du, float& dv)
{
    float tu = traj[(m*2 + 0)*NTI + f];
    float tv = traj[(m*2 + 1)*NTI + f];
    float u = (tu + 0.5f) * (float)GI;
    float v = (tv + 0.5f) * (float)GI;
    float fu = floorf(u), fv = floorf(v);
    du = u - fu; dv = v - fv;
    i0s = (int)fu + GI/2; if (i0s >= GI) i0s -= GI;   // ifftshift folded in
    j0s = (int)fv + GI/2; if (j0s >= GI) j0s -= GI;
}

// ---------------- binning by grid ROW, all frames batched ----------------
__global__ __launch_bounds__(256) void count_rows(
    const float* __restrict__ traj, int* __restrict__ rowcnt)
{
    int tid = blockIdx.x * 256 + threadIdx.x;   // f*MI + m
    int f = tid >> 16, m = tid & (MI - 1);
    int i0s, j0s; float du, dv;
    cell_of(traj, m, f, i0s, j0s, du, dv);
    atomicAdd(&rowcnt[f*GI + i0s], 1);
}

__device__ inline int block_incl_scan(int v, int tid, int* tmp) {
    tmp[tid] = v; __syncthreads();
    for (int d = 1; d < 256; d <<= 1) {
        int y = (tid >= d) ? tmp[tid - d] : 0;
        __syncthreads();
        tmp[tid] += y;
        __syncthreads();
    }
    return tmp[tid];
}

__global__ __launch_bounds__(256) void scan_rows(
    const int* __restrict__ rowcnt, int* __restrict__ rowstart,
    int* __restrict__ rowoff)
{
    __shared__ int tmp[256];
    __shared__ int carry;
    int f = blockIdx.x, tid = threadIdx.x;
    if (tid == 0) carry = 0;
    __syncthreads();
    for (int c = 0; c < GI; c += 256) {
        int i = c + tid;
        int v = (i < GI) ? rowcnt[f*GI + i] : 0;
        int incl = block_incl_scan(v, tid, tmp);
        int excl = carry + incl - v;
        if (i < GI) { rowstart[f*(GI+1) + i] = excl; rowoff[f*GI + i] = excl; }
        int tot = tmp[255];
        __syncthreads();
        if (tid == 0) carry += tot;
        __syncthreads();
    }
    if (tid == 0) rowstart[f*(GI+1) + GI] = MI;
}

__global__ __launch_bounds__(256) void scatter_rows(
    const float* __restrict__ kr, const float* __restrict__ ki,
    const float* __restrict__ traj, const float* __restrict__ dcf,
    int* __restrict__ rowoff, float* __restrict__ recs)
{
    int tid = blockIdx.x * 256 + threadIdx.x;   // f*MI + m
    int f = tid >> 16, m = tid & (MI - 1);
    int i0s, j0s; float du, dv;
    cell_of(traj, m, f, i0s, j0s, du, dv);
    float w = dcf[m*NTI + f];
    int slot = atomicAdd(&rowoff[f*GI + i0s], 1);
    float4* r = (float4*)(recs + ((size_t)f*MI + slot) * REC_F);
    r[0] = make_float4(__int_as_float(j0s), du, dv, 0.f);
    #pragma unroll
    for (int q = 0; q < 4; ++q) {
        int c0 = 2*q;
        r[1+q] = make_float4(kr[c0*MI + m]*w,     ki[c0*MI + m]*w,
                             kr[(c0+1)*MI + m]*w, ki[(c0+1)*MI + m]*w);
    }
}

// ------------- Stockham stage, compile-time radix/size/stride -------------
template<int R, int N, int S>
__device__ inline void stage(const float2* __restrict__ x, float2* __restrict__ y,
                             const float2* __restrict__ W, int lane)
{
    constexpr int m = N / R;
    constexpr int total = m * S;
    for (int item = lane; item < total; item += 64) {
        int p = item / S;            // compile-time divisor
        int q = item - p * S;
        float2 a[R];
        #pragma unroll
        for (int t = 0; t < R; ++t) a[t] = x[q + S*(p + m*t)];
        float2 b[R];
        if constexpr (R == 2) {
            b[0] = make_float2(a[0].x + a[1].x, a[0].y + a[1].y);
            b[1] = make_float2(a[0].x - a[1].x, a[0].y - a[1].y);
        } else if constexpr (R == 4) {
            float2 e0 = make_float2(a[0].x + a[2].x, a[0].y + a[2].y);
            float2 d0 = make_float2(a[0].x - a[2].x, a[0].y - a[2].y);
            float2 e1 = make_float2(a[1].x + a[3].x, a[1].y + a[3].y);
            float2 d1 = make_float2(a[1].x - a[3].x, a[1].y - a[3].y);
            b[0] = make_float2(e0.x + e1.x, e0.y + e1.y);
            b[1] = make_float2(d0.x - d1.y, d0.y + d1.x);
            b[2] = make_float2(e0.x - e1.x, e0.y - e1.y);
            b[3] = make_float2(d0.x + d1.y, d0.y - d1.x);
        } else {  // R == 5
            const float2 w5[5] = {{1.f, 0.f},
                                  { 0.309016994f,  0.951056516f},
                                  {-0.809016994f,  0.587785252f},
                                  {-0.809016994f, -0.587785252f},
                                  { 0.309016994f, -0.951056516f}};
            #pragma unroll
            for (int u = 0; u < 5; ++u) {
                float2 acc = a[0];
                #pragma unroll
                for (int t = 1; t < 5; ++t) {
                    float2 w = w5[(u*t) % 5];
                    acc.x += a[t].x*w.x - a[t].y*w.y;
                    acc.y += a[t].x*w.y + a[t].y*w.x;
                }
                b[u] = acc;
            }
        }
        #pragma unroll
        for (int u = 0; u < R; ++u) {
            float2 tw = W[p * u * S];
            y[q + S*(R*p + u)] = cmul(b[u], tw);
        }
    }
}

// per-wave 640-pt iFFT A[line]->B[line] (ping-pong), no block barriers
template<int LSTRIDE>
__device__ inline void fft640(float2* xA, float2* xB, const float2* W, int lane)
{
    stage<5, 640,   1>(xA, xB, W, lane);
    stage<4, 128,   5>(xB, xA, W, lane);
    stage<4,  32,  20>(xA, xB, W, lane);
    stage<4,   8,  80>(xB, xA, W, lane);
    stage<2,   2, 320>(xA, xB, W, lane);   // result in xB
}

__device__ inline void fill_W(float2* W, int tid, int nthr) {
    for (int j = tid; j < GI; j += nthr) {
        float sj, cj;
        __sincosf((2.0f * 3.14159265358979f / GI) * j, &sj, &cj);
        W[j] = make_float2(cj, sj);     // e^{+2 pi i j / 640}
    }
}

// ---- fused gather + row FFT: block = (frame, grid-row i, coil-half h) ----
__global__ __launch_bounds__(256) void row_fft(
    const int* __restrict__ rowstart, const float* __restrict__ recs,
    float2* __restrict__ rowout)
{
    __shared__ float2 A[4][SP];
    __shared__ float2 B[4][SP];
    __shared__ float2 W[GI];
    int bid = blockIdx.x;               // ((f*640)+i)*2 + h
    int h = bid & 1;
    int i = (bid >> 1) % GI;
    int f = bid / (2*GI);
    int tid = threadIdx.x;
    fill_W(W, tid, 256);
    {
        float2* Az = &A[0][0];
        for (int idx = tid; idx < 4*SP; idx += 256) Az[idx] = make_float2(0.f, 0.f);
    }
    __syncthreads();

    // gather: thread = (record, coil) pair; part 0 = row i (1-du), part 1 = row i-1 (du)
    #pragma unroll
    for (int part = 0; part < 2; ++part) {
        int r = i - part; if (r < 0) r += GI;
        int s0 = rowstart[f*(GI+1) + r];
        int cnt4 = (rowstart[f*(GI+1) + r + 1] - s0) * 4;
        for (int it = tid; it < cnt4; it += 256) {
            int s  = s0 + (it >> 2);
            int cl = it & 3;
            const float2* rec = (const float2*)(recs + ((size_t)f*MI + s) * REC_F);
            float2 hd = rec[0];                 // j0, du
            float  dv = rec[1].x;
            float2 d  = rec[2 + 4*h + cl];      // this coil's (re,im)
            int j0 = __float_as_int(hd.x);
            int j1 = j0 + 1; if (j1 >= GI) j1 -= GI;
            float wr = part ? hd.y : (1.f - hd.y);
            float w0 = wr * (1.f - dv), w1 = wr * dv;
            atomicAdd(&A[cl][j0].x, w0*d.x); atomicAdd(&A[cl][j0].y, w0*d.y);
            atomicAdd(&A[cl][j1].x, w1*d.x); atomicAdd(&A[cl][j1].y, w1*d.y);
        }
    }
    __syncthreads();

    int wv = tid >> 6, lane = tid & 63;   // 4 waves, one line each, no barriers
    fft640<SP>(A[wv], B[wv], W, lane);
    // per-wave cropped write: wave wv owns line wv -> coil 4h+wv
    int coil = 4*h + wv;
    float2* dst = rowout + (((size_t)f*NCI + coil)*GI + i)*NXI;
    for (int yc = lane; yc < NXI; yc += 64) {
        int j = yc + 480; if (j >= GI) j -= GI;
        dst[yc] = B[wv][j];
    }
}

// ---- col FFT + crop: block = (frame, coil, y-group of 4) ----
__global__ __launch_bounds__(256) void col_fft(
    const float2* __restrict__ rowout, float2* __restrict__ colimg)
{
    __shared__ float2 A[4][SP];
    __shared__ float2 B[4][SP];
    __shared__ float2 W[GI];
    int bid = blockIdx.x;               // (f*8 + c)*80 + g
    int g = bid % 80;
    int c = (bid / 80) % NCI;
    int f = bid / (80*NCI);
    int y0 = g * 4;
    int tid = threadIdx.x;
    fill_W(W, tid, 256);
    const float2* src = rowout + ((size_t)f*NCI + c)*GI*NXI + y0;
    for (int idx = tid; idx < 4*GI; idx += 256) {
        int l = idx & 3, k = idx >> 2;
        A[l][k] = src[(size_t)k*NXI + l];
    }
    __syncthreads();
    int wv = tid >> 6, lane = tid & 63;
    fft640<SP>(A[wv], B[wv], W, lane);
    __syncthreads();                    // all lines done before cooperative write
    float2* dst = colimg + ((size_t)f*NCI + c)*NPIX + y0;
    for (int idx = tid; idx < 4*NXI; idx += 256) {
        int l = idx & 3, xx = idx >> 2;
        int j = xx + 480; if (j >= GI) j -= GI;
        dst[(size_t)xx*NXI + l] = B[l][j];
    }
}

// ------------- deapodize + coil combine (crop already folded in) -------------
__global__ __launch_bounds__(256) void combine_kernel(
    const float2* __restrict__ colimg, const float* __restrict__ csr,
    const float* __restrict__ csi, float2* __restrict__ img)
{
    int f = blockIdx.y;
    int pix = blockIdx.x * 256 + threadIdx.x;
    int x = pix / NXI, y = pix - x*NXI;
    const float PI = 3.14159265358979f;
    float tx = (x - 160) * (1.0f/GI);
    float ty = (y - 160) * (1.0f/GI);
    float dx = 1.0f, dy = 1.0f;
    if (x != 160) { float s = __sinf(PI*tx) / (PI*tx); dx = s*s; }
    if (y != 160) { float s = __sinf(PI*ty) / (PI*ty); dy = s*s; }
    float scale = 1.0f / ((float)G2I * dx * dy);
    float accr = 0.f, acci = 0.f;
    #pragma unroll
    for (int c = 0; c < NCI; ++c) {
        float2 g = colimg[((size_t)f*NCI + c)*NPIX + pix];
        float cr = csr[c*NPIX + pix];
        float ci = csi[c*NPIX + pix];
        accr += cr*g.x + ci*g.y;
        acci += cr*g.y - ci*g.x;
    }
    img[(size_t)f*NPIX + pix] = make_float2(accr*scale, acci*scale);
}

// ---------------- warp all frames + sum, write out directly ----------------
__global__ __launch_bounds__(256) void warp_sum(
    const float2* __restrict__ img, const float* __restrict__ motions,
    float* __restrict__ out)
{
    int pix = blockIdx.x * 256 + threadIdx.x;
    int x = pix / NXI, y = pix - x*NXI;
    float accr = 0.f, acci = 0.f;
    #pragma unroll
    for (int f = 0; f < NTI; ++f) {
        float fx = motions[(size_t)(pix*2 + 0)*NTI + f];
        float fy = motions[(size_t)(pix*2 + 1)*NTI + f];
        float xs = fminf(fmaxf((float)x + fx, 0.0f), (float)(NXI-1));
        float ys = fminf(fmaxf((float)y + fy, 0.0f), (float)(NXI-1));
        int x0 = (int)floorf(xs);
        int y0 = (int)floorf(ys);
        int x1 = min(x0+1, NXI-1);
        int y1 = min(y0+1, NXI-1);
        float dx = xs - (float)x0;
        float dy = ys - (float)y0;
        const float2* im = img + (size_t)f*NPIX;
        float2 v00 = im[x0*NXI + y0];
        float2 v10 = im[x1*NXI + y0];
        float2 v01 = im[x0*NXI + y1];
        float2 v11 = im[x1*NXI + y1];
        float w00 = (1.f-dx)*(1.f-dy), w10 = dx*(1.f-dy);
        float w01 = (1.f-dx)*dy,       w11 = dx*dy;
        accr += w00*v00.x + w10*v10.x + w01*v01.x + w11*v11.x;
        acci += w00*v00.y + w10*v10.y + w01*v01.y + w11*v11.y;
    }
    out[pix*2+0] = accr;
    out[pix*2+1] = acci;
}

extern "C" void kernel_launch(void* const* d_in, const int* in_sizes, int n_in,
                              void* d_out, int out_size, void* d_ws, size_t ws_size,
                              hipStream_t stream)
{
    const float* kr   = (const float*)d_in[0];
    const float* ki   = (const float*)d_in[1];
    const float* traj = (const float*)d_in[2];
    const float* csr  = (const float*)d_in[3];
    const float* csi  = (const float*)d_in[4];
    const float* dcf  = (const float*)d_in[5];
    const float* mot  = (const float*)d_in[6];
    float* out = (float*)d_out;

    char* ws = (char*)d_ws;
    float*  recs     = (float*)ws;                       // 41.94 MB
    ws += (size_t)NTI * MI * REC_F * sizeof(float);
    float2* rowout   = (float2*)ws;                      // 104.86 MB
    ws += (size_t)NTI * NCI * GI * NXI * sizeof(float2);
    float2* colimg   = (float2*)ws;                      // 52.43 MB
    ws += (size_t)NTI * NCI * NPIX * sizeof(float2);
    float2* img      = (float2*)ws;                      // 6.55 MB
    ws += (size_t)NTI * NPIX * sizeof(float2);
    int*    rowcnt   = (int*)ws;  ws += (size_t)NTI * GI * sizeof(int);
    int*    rowstart = (int*)ws;  ws += (size_t)NTI * (GI+1) * sizeof(int) + 64;
    int*    rowoff   = (int*)ws;  ws += (size_t)NTI * GI * sizeof(int);

    hipMemsetAsync(rowcnt, 0, (size_t)NTI * GI * sizeof(int), stream);
    count_rows  <<<NTI*MI/256, 256, 0, stream>>>(traj, rowcnt);
    scan_rows   <<<NTI,        256, 0, stream>>>(rowcnt, rowstart, rowoff);
    scatter_rows<<<NTI*MI/256, 256, 0, stream>>>(kr, ki, traj, dcf, rowoff, recs);
    row_fft     <<<NTI*GI*2,   256, 0, stream>>>(rowstart, recs, rowout);
    col_fft     <<<NTI*NCI*80, 256, 0, stream>>>(rowout, colimg);
    combine_kernel<<<dim3(NPIX/256, NTI), 256, 0, stream>>>(colimg, csr, csi, img);
    warp_sum    <<<NPIX/256,   256, 0, stream>>>(img, mot, out);
}

// Round 5
// 501.433 us; speedup vs baseline: 4.5810x; 1.0979x over previous
//
#include <hip/hip_runtime.h>
#include <math.h>

#define NXI 320
#define NCI 8
#define NTI 8
#define MI  65536
#define GI  640
#define G2I (GI*GI)
#define NPIX (NXI*NXI)
#define REC_F 20     // floats per record: {j0,du,dv,pad, 8x(re,im)}
#define SP 642       // padded LDS line stride (float2)

__device__ inline float2 cmul(float2 a, float2 b) {
    return make_float2(a.x*b.x - a.y*b.y, a.x*b.y + a.y*b.x);
}
__device__ inline float2 cadd(float2 a, float2 b) { return make_float2(a.x+b.x, a.y+b.y); }
__device__ inline float2 csub(float2 a, float2 b) { return make_float2(a.x-b.x, a.y-b.y); }

__device__ inline float2 shfl_xor_c(float2 v, int m) {
    return make_float2(__shfl_xor(v.x, m, 64), __shfl_xor(v.y, m, 64));
}

__device__ inline void cell_of(const float* __restrict__ traj, int m, int f,
                               int& i0s, int& j0s, float& du, float& dv)
{
    float tu = traj[(m*2 + 0)*NTI + f];
    float tv = traj[(m*2 + 1)*NTI + f];
    float u = (tu + 0.5f) * (float)GI;
    float v = (tv + 0.5f) * (float)GI;
    float fu = floorf(u), fv = floorf(v);
    du = u - fu; dv = v - fv;
    i0s = (int)fu + GI/2; if (i0s >= GI) i0s -= GI;   // ifftshift folded in
    j0s = (int)fv + GI/2; if (j0s >= GI) j0s -= GI;
}

// ---------------- binning by grid ROW, all frames batched ----------------
__global__ __launch_bounds__(256) void count_rows(
    const float* __restrict__ traj, int* __restrict__ rowcnt)
{
    int tid = blockIdx.x * 256 + threadIdx.x;   // f*MI + m
    int f = tid >> 16, m = tid & (MI - 1);
    int i0s, j0s; float du, dv;
    cell_of(traj, m, f, i0s, j0s, du, dv);
    atomicAdd(&rowcnt[f*GI + i0s], 1);
}

__device__ inline int block_incl_scan(int v, int tid, int* tmp) {
    tmp[tid] = v; __syncthreads();
    for (int d = 1; d < 256; d <<= 1) {
        int y = (tid >= d) ? tmp[tid - d] : 0;
        __syncthreads();
        tmp[tid] += y;
        __syncthreads();
    }
    return tmp[tid];
}

__global__ __launch_bounds__(256) void scan_rows(
    const int* __restrict__ rowcnt, int* __restrict__ rowstart,
    int* __restrict__ rowoff)
{
    __shared__ int tmp[256];
    __shared__ int carry;
    int f = blockIdx.x, tid = threadIdx.x;
    if (tid == 0) carry = 0;
    __syncthreads();
    for (int c = 0; c < GI; c += 256) {
        int i = c + tid;
        int v = (i < GI) ? rowcnt[f*GI + i] : 0;
        int incl = block_incl_scan(v, tid, tmp);
        int excl = carry + incl - v;
        if (i < GI) { rowstart[f*(GI+1) + i] = excl; rowoff[f*GI + i] = excl; }
        int tot = tmp[255];
        __syncthreads();
        if (tid == 0) carry += tot;
        __syncthreads();
    }
    if (tid == 0) rowstart[f*(GI+1) + GI] = MI;
}

__global__ __launch_bounds__(256) void scatter_rows(
    const float* __restrict__ kr, const float* __restrict__ ki,
    const float* __restrict__ traj, const float* __restrict__ dcf,
    int* __restrict__ rowoff, float* __restrict__ recs)
{
    int tid = blockIdx.x * 256 + threadIdx.x;   // f*MI + m
    int f = tid >> 16, m = tid & (MI - 1);
    int i0s, j0s; float du, dv;
    cell_of(traj, m, f, i0s, j0s, du, dv);
    float w = dcf[m*NTI + f];
    int slot = atomicAdd(&rowoff[f*GI + i0s], 1);
    float4* r = (float4*)(recs + ((size_t)f*MI + slot) * REC_F);
    r[0] = make_float4(__int_as_float(j0s), du, dv, 0.f);
    #pragma unroll
    for (int q = 0; q < 4; ++q) {
        int c0 = 2*q;
        r[1+q] = make_float4(kr[c0*MI + m]*w,     ki[c0*MI + m]*w,
                             kr[(c0+1)*MI + m]*w, ki[(c0+1)*MI + m]*w);
    }
}

// ---------------- register-resident 640-pt iFFT (sign +) ----------------
// data: lane L holds x[10*L + n2] in a[n2], n2=0..9.
// produces X[j] for j = k1 + 64*k2, k1 = bitrev6(L); a[k2] slot order via callback.

__device__ inline void dft5p(float2 x0, float2 x1, float2 x2, float2 x3, float2 x4,
                             float2* X)   // X[u] = sum x[t] e^{+2pi i ut/5}
{
    const float c1 = 0.309016994f, c2 = -0.809016994f;
    const float s1 = 0.951056516f, s2 =  0.587785252f;
    float2 S1 = cadd(x1, x4), D1 = csub(x1, x4);
    float2 S2 = cadd(x2, x3), D2 = csub(x2, x3);
    X[0] = make_float2(x0.x + S1.x + S2.x, x0.y + S1.y + S2.y);
    float2 A = make_float2(x0.x + c1*S1.x + c2*S2.x, x0.y + c1*S1.y + c2*S2.y);
    float2 T = make_float2(s1*D1.x + s2*D2.x,        s1*D1.y + s2*D2.y);
    float2 B = make_float2(x0.x + c2*S1.x + c1*S2.x, x0.y + c2*S1.y + c1*S2.y);
    float2 U = make_float2(s2*D1.x - s1*D2.x,        s2*D1.y - s1*D2.y);
    X[1] = make_float2(A.x - T.y, A.y + T.x);   // A + iT
    X[4] = make_float2(A.x + T.y, A.y - T.x);   // A - iT
    X[2] = make_float2(B.x - U.y, B.y + U.x);   // B + iU
    X[3] = make_float2(B.x + U.y, B.y - U.x);   // B - iU
}

// In-register FFT; afterwards Z[k2] available; caller stores via lambda-ish macro.
// Writes results into out[k2] (k2 = 0..9) and returns k1.
__device__ inline int fft640_reg(float2* a, int lane, float2* Z)
{
    const float PI = 3.14159265358979f;
    // 6 across-lane DIF stages
    #pragma unroll
    for (int s = 0; s < 6; ++s) {
        const int h = 32 >> s;
        int r = lane & (2*h - 1);
        bool low = r < h;
        float sgn = low ? 1.f : -1.f;
        float th = PI * (float)(r - h) / (float)h;
        float sn, cs;
        __sincosf(th, &sn, &cs);
        float2 w = low ? make_float2(1.f, 0.f) : make_float2(cs, sn);
        #pragma unroll
        for (int n = 0; n < 10; ++n) {
            float2 p = shfl_xor_c(a[n], h);
            float2 t = make_float2(fmaf(sgn, a[n].x, p.x), fmaf(sgn, a[n].y, p.y));
            a[n] = cmul(t, w);
        }
    }
    int k1 = __brev(lane) >> 26;
    // twiddle e^{+2pi i n2 k1 / 640}
    float th = (2.0f * PI / 640.0f) * (float)k1;
    float sn, cs;
    __sincosf(th, &sn, &cs);
    float2 wb = make_float2(cs, sn);
    float2 w = wb;
    #pragma unroll
    for (int n = 1; n < 10; ++n) {
        a[n] = cmul(a[n], w);
        w = cmul(w, wb);
    }
    // DFT-10 = even/odd DFT-5 + combine
    float2 E[5], O[5];
    dft5p(a[0], a[2], a[4], a[6], a[8], E);
    dft5p(a[1], a[3], a[5], a[7], a[9], O);
    const float2 tk[5] = {{1.f, 0.f},
                          { 0.809016994f, 0.587785252f},
                          { 0.309016994f, 0.951056516f},
                          {-0.309016994f, 0.951056516f},
                          {-0.809016994f, 0.587785252f}};
    #pragma unroll
    for (int k = 0; k < 5; ++k) {
        float2 t = cmul(tk[k], O[k]);
        Z[k]     = cadd(E[k], t);
        Z[k + 5] = csub(E[k], t);
    }
    return k1;
}

// ---- fused gather + row FFT: block = (frame, grid-row i), 8 coils = 8 waves ----
__global__ __launch_bounds__(512) void row_fft(
    const int* __restrict__ rowstart, const float* __restrict__ recs,
    float2* __restrict__ rowout)
{
    __shared__ float2 A[NCI][SP];
    int bid = blockIdx.x;               // f*GI + i
    int i = bid % GI;
    int f = bid / GI;
    int tid = threadIdx.x;
    {
        float2* Az = &A[0][0];
        for (int idx = tid; idx < NCI*SP; idx += 512) Az[idx] = make_float2(0.f, 0.f);
    }
    __syncthreads();

    // gather: thread = (record, coil); part 0 = bin-row i (1-du), part 1 = row i-1 (du)
    #pragma unroll
    for (int part = 0; part < 2; ++part) {
        int r = i - part; if (r < 0) r += GI;
        int s0 = rowstart[f*(GI+1) + r];
        int cnt8 = (rowstart[f*(GI+1) + r + 1] - s0) * 8;
        for (int it = tid; it < cnt8; it += 512) {
            int s  = s0 + (it >> 3);
            int cl = it & 7;
            const float2* rec = (const float2*)(recs + ((size_t)f*MI + s) * REC_F);
            float2 hd = rec[0];                 // j0, du
            float  dv = rec[1].x;
            float2 d  = rec[2 + cl];            // this coil's (re,im)
            int j0 = __float_as_int(hd.x);
            int j1 = j0 + 1; if (j1 >= GI) j1 -= GI;
            float wr = part ? hd.y : (1.f - hd.y);
            float w0 = wr * (1.f - dv), w1 = wr * dv;
            atomicAdd(&A[cl][j0].x, w0*d.x); atomicAdd(&A[cl][j0].y, w0*d.y);
            atomicAdd(&A[cl][j1].x, w1*d.x); atomicAdd(&A[cl][j1].y, w1*d.y);
        }
    }
    __syncthreads();

    int wv = tid >> 6, lane = tid & 63;   // wave wv owns coil wv
    float2 a[10];
    #pragma unroll
    for (int n = 0; n < 10; ++n) a[n] = A[wv][10*lane + n];
    float2 Z[10];
    int k1 = fft640_reg(a, lane, Z);
    // stage cropped output into own LDS row (yc = (j+160) mod 640), then store
    #pragma unroll
    for (int k2 = 0; k2 < 10; ++k2) {
        int yc = k1 + 64*k2 + 160; if (yc >= GI) yc -= GI;
        A[wv][yc] = Z[k2];
    }
    // own-wave data only: no barrier needed
    float2* dst = rowout + (((size_t)f*NCI + wv)*GI + i)*NXI;
    #pragma unroll
    for (int q = 0; q < 5; ++q) {
        int yc = lane + 64*q;
        dst[yc] = A[wv][yc];
    }
}

// ---- col FFT + crop: block = (frame, coil, y-group of 8) ----
__global__ __launch_bounds__(512) void col_fft(
    const float2* __restrict__ rowout, float2* __restrict__ colimg)
{
    __shared__ float2 A[8][SP];
    int bid = blockIdx.x;               // (f*NCI + c)*40 + g
    int g = bid % 40;
    int c = (bid / 40) % NCI;
    int f = bid / (40*NCI);
    int y0 = g * 8;
    int tid = threadIdx.x;
    const float2* src = rowout + ((size_t)f*NCI + c)*GI*NXI + y0;
    for (int idx = tid; idx < 8*GI; idx += 512) {
        int l = idx & 7, k = idx >> 3;
        A[l][k] = src[(size_t)k*NXI + l];
    }
    __syncthreads();
    int wv = tid >> 6, lane = tid & 63;   // wave wv owns y = y0 + wv
    float2 a[10];
    #pragma unroll
    for (int n = 0; n < 10; ++n) a[n] = A[wv][10*lane + n];
    float2 Z[10];
    int k1 = fft640_reg(a, lane, Z);
    #pragma unroll
    for (int k2 = 0; k2 < 10; ++k2) {
        int xx = k1 + 64*k2 + 160; if (xx >= GI) xx -= GI;
        A[wv][xx] = Z[k2];
    }
    __syncthreads();                    // transpose write needs all waves
    float2* dst = colimg + ((size_t)f*NCI + c)*NPIX + y0;
    for (int idx = tid; idx < 8*NXI; idx += 512) {
        int l = idx & 7, xx = idx >> 3;
        dst[(size_t)xx*NXI + l] = A[l][xx];
    }
}

// ------------- deapodize + coil combine (crop already folded in) -------------
__global__ __launch_bounds__(256) void combine_kernel(
    const float2* __restrict__ colimg, const float* __restrict__ csr,
    const float* __restrict__ csi, float2* __restrict__ img)
{
    int f = blockIdx.y;
    int pix = blockIdx.x * 256 + threadIdx.x;
    int x = pix / NXI, y = pix - x*NXI;
    const float PI = 3.14159265358979f;
    float tx = (x - 160) * (1.0f/GI);
    float ty = (y - 160) * (1.0f/GI);
    float dx = 1.0f, dy = 1.0f;
    if (x != 160) { float s = __sinf(PI*tx) / (PI*tx); dx = s*s; }
    if (y != 160) { float s = __sinf(PI*ty) / (PI*ty); dy = s*s; }
    float scale = 1.0f / ((float)G2I * dx * dy);
    float accr = 0.f, acci = 0.f;
    #pragma unroll
    for (int c = 0; c < NCI; ++c) {
        float2 g = colimg[((size_t)f*NCI + c)*NPIX + pix];
        float cr = csr[c*NPIX + pix];
        float ci = csi[c*NPIX + pix];
        accr += cr*g.x + ci*g.y;
        acci += cr*g.y - ci*g.x;
    }
    img[(size_t)f*NPIX + pix] = make_float2(accr*scale, acci*scale);
}

// ---------------- warp all frames + sum, write out directly ----------------
__global__ __launch_bounds__(256) void warp_sum(
    const float2* __restrict__ img, const float* __restrict__ motions,
    float* __restrict__ out)
{
    int pix = blockIdx.x * 256 + threadIdx.x;
    int x = pix / NXI, y = pix - x*NXI;
    float accr = 0.f, acci = 0.f;
    #pragma unroll
    for (int f = 0; f < NTI; ++f) {
        float fx = motions[(size_t)(pix*2 + 0)*NTI + f];
        float fy = motions[(size_t)(pix*2 + 1)*NTI + f];
        float xs = fminf(fmaxf((float)x + fx, 0.0f), (float)(NXI-1));
        float ys = fminf(fmaxf((float)y + fy, 0.0f), (float)(NXI-1));
        int x0 = (int)floorf(xs);
        int y0 = (int)floorf(ys);
        int x1 = min(x0+1, NXI-1);
        int y1 = min(y0+1, NXI-1);
        float dx = xs - (float)x0;
        float dy = ys - (float)y0;
        const float2* im = img + (size_t)f*NPIX;
        float2 v00 = im[x0*NXI + y0];
        float2 v10 = im[x1*NXI + y0];
        float2 v01 = im[x0*NXI + y1];
        float2 v11 = im[x1*NXI + y1];
        float w00 = (1.f-dx)*(1.f-dy), w10 = dx*(1.f-dy);
        float w01 = (1.f-dx)*dy,       w11 = dx*dy;
        accr += w00*v00.x + w10*v10.x + w01*v01.x + w11*v11.x;
        acci += w00*v00.y + w10*v10.y + w01*v01.y + w11*v11.y;
    }
    out[pix*2+0] = accr;
    out[pix*2+1] = acci;
}

extern "C" void kernel_launch(void* const* d_in, const int* in_sizes, int n_in,
                              void* d_out, int out_size, void* d_ws, size_t ws_size,
                              hipStream_t stream)
{
    const float* kr   = (const float*)d_in[0];
    const float* ki   = (const float*)d_in[1];
    const float* traj = (const float*)d_in[2];
    const float* csr  = (const float*)d_in[3];
    const float* csi  = (const float*)d_in[4];
    const float* dcf  = (const float*)d_in[5];
    const float* mot  = (const float*)d_in[6];
    float* out = (float*)d_out;

    char* ws = (char*)d_ws;
    float*  recs     = (float*)ws;                       // 41.94 MB
    ws += (size_t)NTI * MI * REC_F * sizeof(float);
    float2* rowout   = (float2*)ws;                      // 104.86 MB
    ws += (size_t)NTI * NCI * GI * NXI * sizeof(float2);
    float2* colimg   = (float2*)ws;                      // 52.43 MB
    ws += (size_t)NTI * NCI * NPIX * sizeof(float2);
    float2* img      = (float2*)ws;                      // 6.55 MB
    ws += (size_t)NTI * NPIX * sizeof(float2);
    int*    rowcnt   = (int*)ws;  ws += (size_t)NTI * GI * sizeof(int);
    int*    rowstart = (int*)ws;  ws += (size_t)NTI * (GI+1) * sizeof(int) + 64;
    int*    rowoff   = (int*)ws;  ws += (size_t)NTI * GI * sizeof(int);

    hipMemsetAsync(rowcnt, 0, (size_t)NTI * GI * sizeof(int), stream);
    count_rows  <<<NTI*MI/256, 256, 0, stream>>>(traj, rowcnt);
    scan_rows   <<<NTI,        256, 0, stream>>>(rowcnt, rowstart, rowoff);
    scatter_rows<<<NTI*MI/256, 256, 0, stream>>>(kr, ki, traj, dcf, rowoff, recs);
    row_fft     <<<NTI*GI,     512, 0, stream>>>(rowstart, recs, rowout);
    col_fft     <<<NTI*NCI*40, 512, 0, stream>>>(rowout, colimg);
    combine_kernel<<<dim3(NPIX/256, NTI), 256, 0, stream>>>(colimg, csr, csi, img);
    warp_sum    <<<NPIX/256,   256, 0, stream>>>(img, mot, out);
}

// Round 6
// 433.830 us; speedup vs baseline: 5.2949x; 1.1558x over previous
//
#include <hip/hip_runtime.h>
#include <math.h>

#define NXI 320
#define NCI 8
#define NTI 8
#define MI  65536
#define GI  640
#define G2I (GI*GI)
#define NPIX (NXI*NXI)
#define REC_F 20          // floats per record: {du,dv,0,0, 8x(re,im)}
#define SP 642            // padded LDS line stride (float2)
#define NBINS (NTI*G2I)   // 3,276,800 cells over all frames
#define SCAN_BLKS (NBINS/256)   // 12800

__device__ inline float2 cmul(float2 a, float2 b) {
    return make_float2(a.x*b.x - a.y*b.y, a.x*b.y + a.y*b.x);
}
__device__ inline float2 cadd(float2 a, float2 b) { return make_float2(a.x+b.x, a.y+b.y); }
__device__ inline float2 csub(float2 a, float2 b) { return make_float2(a.x-b.x, a.y-b.y); }

__device__ inline float2 shfl_xor_c(float2 v, int m) {
    return make_float2(__shfl_xor(v.x, m, 64), __shfl_xor(v.y, m, 64));
}

__device__ inline void cell_of(const float* __restrict__ traj, int m, int f,
                               int& i0s, int& j0s, float& du, float& dv)
{
    float tu = traj[(m*2 + 0)*NTI + f];
    float tv = traj[(m*2 + 1)*NTI + f];
    float u = (tu + 0.5f) * (float)GI;
    float v = (tv + 0.5f) * (float)GI;
    float fu = floorf(u), fv = floorf(v);
    du = u - fu; dv = v - fv;
    i0s = (int)fu + GI/2; if (i0s >= GI) i0s -= GI;   // ifftshift folded in
    j0s = (int)fv + GI/2; if (j0s >= GI) j0s -= GI;
}

// ---------------- cell-level counting sort, all frames ----------------
__global__ __launch_bounds__(256) void count_cells(
    const float* __restrict__ traj, int* __restrict__ counts)
{
    int tid = blockIdx.x * 256 + threadIdx.x;   // f*MI + m
    int f = tid >> 16, m = tid & (MI - 1);
    int i0s, j0s; float du, dv;
    cell_of(traj, m, f, i0s, j0s, du, dv);
    atomicAdd(&counts[f*G2I + i0s*GI + j0s], 1);
}

__device__ inline int block_incl_scan(int v, int tid, int* tmp) {
    tmp[tid] = v; __syncthreads();
    for (int d = 1; d < 256; d <<= 1) {
        int y = (tid >= d) ? tmp[tid - d] : 0;
        __syncthreads();
        tmp[tid] += y;
        __syncthreads();
    }
    return tmp[tid];
}

__global__ __launch_bounds__(256) void scanA(const int* __restrict__ counts,
                                             int* __restrict__ binstart,
                                             int* __restrict__ sums)
{
    __shared__ int tmp[256];
    int tid = threadIdx.x;
    int i = blockIdx.x * 256 + tid;
    int v = counts[i];
    int incl = block_incl_scan(v, tid, tmp);
    binstart[i] = incl - v;                   // local exclusive
    if (tid == 255) sums[blockIdx.x] = incl;  // block total
}

__global__ __launch_bounds__(256) void scanB(int* __restrict__ sums)
{
    __shared__ int tmp[256];
    __shared__ int carry;
    int tid = threadIdx.x;
    if (tid == 0) carry = 0;
    __syncthreads();
    for (int c = 0; c < SCAN_BLKS; c += 256) {
        int i = c + tid;
        int v = sums[i];
        int incl = block_incl_scan(v, tid, tmp);
        int tot = tmp[255];
        sums[i] = carry + incl - v;
        __syncthreads();
        if (tid == 0) carry += tot;
        __syncthreads();
    }
}

__global__ __launch_bounds__(256) void scanC(int* __restrict__ binstart,
                                             const int* __restrict__ sums,
                                             int* __restrict__ cursor)
{
    int i = blockIdx.x * 256 + threadIdx.x;
    int v = binstart[i] + sums[blockIdx.x];
    binstart[i] = v;
    cursor[i] = v;
    if (i == NBINS - 1) binstart[NBINS] = NTI * MI;   // global sentinel
}

__global__ __launch_bounds__(256) void scatter_cells(
    const float* __restrict__ kr, const float* __restrict__ ki,
    const float* __restrict__ traj, const float* __restrict__ dcf,
    int* __restrict__ cursor, float* __restrict__ recs)
{
    int tid = blockIdx.x * 256 + threadIdx.x;   // f*MI + m
    int f = tid >> 16, m = tid & (MI - 1);
    int i0s, j0s; float du, dv;
    cell_of(traj, m, f, i0s, j0s, du, dv);
    float w = dcf[m*NTI + f];
    int slot = atomicAdd(&cursor[f*G2I + i0s*GI + j0s], 1);   // global slot
    float4* r = (float4*)(recs + (size_t)slot * REC_F);
    r[0] = make_float4(du, dv, 0.f, 0.f);
    #pragma unroll
    for (int q = 0; q < 4; ++q) {
        int c0 = 2*q;
        r[1+q] = make_float4(kr[c0*MI + m]*w,     ki[c0*MI + m]*w,
                             kr[(c0+1)*MI + m]*w, ki[(c0+1)*MI + m]*w);
    }
}

// ---------------- register-resident 640-pt iFFT (sign +) ----------------
__device__ inline void dft5p(float2 x0, float2 x1, float2 x2, float2 x3, float2 x4,
                             float2* X)   // X[u] = sum x[t] e^{+2pi i ut/5}
{
    const float c1 = 0.309016994f, c2 = -0.809016994f;
    const float s1 = 0.951056516f, s2 =  0.587785252f;
    float2 S1 = cadd(x1, x4), D1 = csub(x1, x4);
    float2 S2 = cadd(x2, x3), D2 = csub(x2, x3);
    X[0] = make_float2(x0.x + S1.x + S2.x, x0.y + S1.y + S2.y);
    float2 A = make_float2(x0.x + c1*S1.x + c2*S2.x, x0.y + c1*S1.y + c2*S2.y);
    float2 T = make_float2(s1*D1.x + s2*D2.x,        s1*D1.y + s2*D2.y);
    float2 B = make_float2(x0.x + c2*S1.x + c1*S2.x, x0.y + c2*S1.y + c1*S2.y);
    float2 U = make_float2(s2*D1.x - s1*D2.x,        s2*D1.y - s1*D2.y);
    X[1] = make_float2(A.x - T.y, A.y + T.x);
    X[4] = make_float2(A.x + T.y, A.y - T.x);
    X[2] = make_float2(B.x - U.y, B.y + U.x);
    X[3] = make_float2(B.x + U.y, B.y - U.x);
}

__device__ inline int fft640_reg(float2* a, int lane, float2* Z)
{
    const float PI = 3.14159265358979f;
    #pragma unroll
    for (int s = 0; s < 6; ++s) {
        const int h = 32 >> s;
        int r = lane & (2*h - 1);
        bool low = r < h;
        float sgn = low ? 1.f : -1.f;
        float th = PI * (float)(r - h) / (float)h;
        float sn, cs;
        __sincosf(th, &sn, &cs);
        float2 w = low ? make_float2(1.f, 0.f) : make_float2(cs, sn);
        #pragma unroll
        for (int n = 0; n < 10; ++n) {
            float2 p = shfl_xor_c(a[n], h);
            float2 t = make_float2(fmaf(sgn, a[n].x, p.x), fmaf(sgn, a[n].y, p.y));
            a[n] = cmul(t, w);
        }
    }
    int k1 = __brev(lane) >> 26;
    float th = (2.0f * PI / 640.0f) * (float)k1;
    float sn, cs;
    __sincosf(th, &sn, &cs);
    float2 wb = make_float2(cs, sn);
    float2 w = wb;
    #pragma unroll
    for (int n = 1; n < 10; ++n) {
        a[n] = cmul(a[n], w);
        w = cmul(w, wb);
    }
    float2 E[5], O[5];
    dft5p(a[0], a[2], a[4], a[6], a[8], E);
    dft5p(a[1], a[3], a[5], a[7], a[9], O);
    const float2 tk[5] = {{1.f, 0.f},
                          { 0.809016994f, 0.587785252f},
                          { 0.309016994f, 0.951056516f},
                          {-0.309016994f, 0.951056516f},
                          {-0.809016994f, 0.587785252f}};
    #pragma unroll
    for (int k = 0; k < 5; ++k) {
        float2 t = cmul(tk[k], O[k]);
        Z[k]     = cadd(E[k], t);
        Z[k + 5] = csub(E[k], t);
    }
    return k1;
}

// ---- fused atomic-free gather + row FFT: block = (frame, grid-row i) ----
__global__ __launch_bounds__(512) void row_fft(
    const int* __restrict__ binstart, const float* __restrict__ recs,
    float2* __restrict__ rowout)
{
    __shared__ float2 A[NCI][SP];
    __shared__ int boff[2][GI+1];
    int bid = blockIdx.x;               // f*GI + i
    int i = bid % GI;
    int f = bid / GI;
    int tid = threadIdx.x;
    int im1 = i ? i - 1 : GI - 1;
    const int base0 = f*G2I + i*GI;     // part 0: bin-row i   (row weight 1-du)
    const int base1 = f*G2I + im1*GI;   // part 1: bin-row i-1 (row weight du)
    for (int k = tid; k <= GI; k += 512) {
        boff[0][k] = binstart[base0 + k];
        boff[1][k] = binstart[base1 + k];
    }
    __syncthreads();

    // each thread owns (output cell j, coil c) exclusively — no atomics
    for (int item = tid; item < GI*NCI; item += 512) {
        int j = item >> 3, c = item & 7;
        int jm1 = j ? j - 1 : GI - 1;
        float2 acc = make_float2(0.f, 0.f);
        #pragma unroll
        for (int p = 0; p < 2; ++p) {
            // bin b = j: col weight (1-dv)
            int s1 = boff[p][j+1];
            for (int s = boff[p][j]; s < s1; ++s) {
                const float2* rec = (const float2*)(recs + (size_t)s*REC_F);
                float2 hd = rec[0];                 // du, dv
                float wr = p ? hd.x : (1.f - hd.x);
                float w = wr * (1.f - hd.y);
                float2 d = rec[2 + c];
                acc.x += w*d.x; acc.y += w*d.y;
            }
            // bin b = j-1 (wrap-safe): col weight dv
            int s3 = boff[p][jm1+1];
            for (int s = boff[p][jm1]; s < s3; ++s) {
                const float2* rec = (const float2*)(recs + (size_t)s*REC_F);
                float2 hd = rec[0];
                float wr = p ? hd.x : (1.f - hd.x);
                float w = wr * hd.y;
                float2 d = rec[2 + c];
                acc.x += w*d.x; acc.y += w*d.y;
            }
        }
        A[c][j] = acc;
    }
    __syncthreads();

    int wv = tid >> 6, lane = tid & 63;   // wave wv owns coil wv
    float2 a[10];
    #pragma unroll
    for (int n = 0; n < 10; ++n) a[n] = A[wv][10*lane + n];
    float2 Z[10];
    int k1 = fft640_reg(a, lane, Z);
    #pragma unroll
    for (int k2 = 0; k2 < 10; ++k2) {
        int yc = k1 + 64*k2 + 160; if (yc >= GI) yc -= GI;
        A[wv][yc] = Z[k2];
    }
    // own-wave data only: no barrier needed
    float2* dst = rowout + (((size_t)f*NCI + wv)*GI + i)*NXI;
    #pragma unroll
    for (int q = 0; q < 5; ++q) {
        int yc = lane + 64*q;
        dst[yc] = A[wv][yc];
    }
}

// ---- col FFT + crop: block = (frame, coil, y-group of 8) ----
__global__ __launch_bounds__(512) void col_fft(
    const float2* __restrict__ rowout, float2* __restrict__ colimg)
{
    __shared__ float2 A[8][SP];
    int bid = blockIdx.x;               // (f*NCI + c)*40 + g
    int g = bid % 40;
    int c = (bid / 40) % NCI;
    int f = bid / (40*NCI);
    int y0 = g * 8;
    int tid = threadIdx.x;
    const float2* src = rowout + ((size_t)f*NCI + c)*GI*NXI + y0;
    for (int idx = tid; idx < 8*GI; idx += 512) {
        int l = idx & 7, k = idx >> 3;
        A[l][k] = src[(size_t)k*NXI + l];
    }
    __syncthreads();
    int wv = tid >> 6, lane = tid & 63;
    float2 a[10];
    #pragma unroll
    for (int n = 0; n < 10; ++n) a[n] = A[wv][10*lane + n];
    float2 Z[10];
    int k1 = fft640_reg(a, lane, Z);
    #pragma unroll
    for (int k2 = 0; k2 < 10; ++k2) {
        int xx = k1 + 64*k2 + 160; if (xx >= GI) xx -= GI;
        A[wv][xx] = Z[k2];
    }
    __syncthreads();
    float2* dst = colimg + ((size_t)f*NCI + c)*NPIX + y0;
    for (int idx = tid; idx < 8*NXI; idx += 512) {
        int l = idx & 7, xx = idx >> 3;
        dst[(size_t)xx*NXI + l] = A[l][xx];
    }
}

// ------------- deapodize + coil combine -------------
__global__ __launch_bounds__(256) void combine_kernel(
    const float2* __restrict__ colimg, const float* __restrict__ csr,
    const float* __restrict__ csi, float2* __restrict__ img)
{
    int f = blockIdx.y;
    int pix = blockIdx.x * 256 + threadIdx.x;
    int x = pix / NXI, y = pix - x*NXI;
    const float PI = 3.14159265358979f;
    float tx = (x - 160) * (1.0f/GI);
    float ty = (y - 160) * (1.0f/GI);
    float dx = 1.0f, dy = 1.0f;
    if (x != 160) { float s = __sinf(PI*tx) / (PI*tx); dx = s*s; }
    if (y != 160) { float s = __sinf(PI*ty) / (PI*ty); dy = s*s; }
    float scale = 1.0f / ((float)G2I * dx * dy);
    float accr = 0.f, acci = 0.f;
    #pragma unroll
    for (int c = 0; c < NCI; ++c) {
        float2 g = colimg[((size_t)f*NCI + c)*NPIX + pix];
        float cr = csr[c*NPIX + pix];
        float ci = csi[c*NPIX + pix];
        accr += cr*g.x + ci*g.y;
        acci += cr*g.y - ci*g.x;
    }
    img[(size_t)f*NPIX + pix] = make_float2(accr*scale, acci*scale);
}

// ---------------- warp all frames + sum ----------------
__global__ __launch_bounds__(256) void warp_sum(
    const float2* __restrict__ img, const float* __restrict__ motions,
    float* __restrict__ out)
{
    int pix = blockIdx.x * 256 + threadIdx.x;
    int x = pix / NXI, y = pix - x*NXI;
    float accr = 0.f, acci = 0.f;
    #pragma unroll
    for (int f = 0; f < NTI; ++f) {
        float fx = motions[(size_t)(pix*2 + 0)*NTI + f];
        float fy = motions[(size_t)(pix*2 + 1)*NTI + f];
        float xs = fminf(fmaxf((float)x + fx, 0.0f), (float)(NXI-1));
        float ys = fminf(fmaxf((float)y + fy, 0.0f), (float)(NXI-1));
        int x0 = (int)floorf(xs);
        int y0 = (int)floorf(ys);
        int x1 = min(x0+1, NXI-1);
        int y1 = min(y0+1, NXI-1);
        float dx = xs - (float)x0;
        float dy = ys - (float)y0;
        const float2* im = img + (size_t)f*NPIX;
        float2 v00 = im[x0*NXI + y0];
        float2 v10 = im[x1*NXI + y0];
        float2 v01 = im[x0*NXI + y1];
        float2 v11 = im[x1*NXI + y1];
        float w00 = (1.f-dx)*(1.f-dy), w10 = dx*(1.f-dy);
        float w01 = (1.f-dx)*dy,       w11 = dx*dy;
        accr += w00*v00.x + w10*v10.x + w01*v01.x + w11*v11.x;
        acci += w00*v00.y + w10*v10.y + w01*v01.y + w11*v11.y;
    }
    out[pix*2+0] = accr;
    out[pix*2+1] = acci;
}

extern "C" void kernel_launch(void* const* d_in, const int* in_sizes, int n_in,
                              void* d_out, int out_size, void* d_ws, size_t ws_size,
                              hipStream_t stream)
{
    const float* kr   = (const float*)d_in[0];
    const float* ki   = (const float*)d_in[1];
    const float* traj = (const float*)d_in[2];
    const float* csr  = (const float*)d_in[3];
    const float* csi  = (const float*)d_in[4];
    const float* dcf  = (const float*)d_in[5];
    const float* mot  = (const float*)d_in[6];
    float* out = (float*)d_out;

    char* ws = (char*)d_ws;
    float*  recs     = (float*)ws;                       // 41.94 MB
    ws += (size_t)NTI * MI * REC_F * sizeof(float);
    float2* rowout   = (float2*)ws;                      // 104.86 MB
    ws += (size_t)NTI * NCI * GI * NXI * sizeof(float2);
    float2* colimg   = (float2*)ws;                      // 52.43 MB
    ws += (size_t)NTI * NCI * NPIX * sizeof(float2);
    float2* img      = (float2*)ws;                      // 6.55 MB
    ws += (size_t)NTI * NPIX * sizeof(float2);
    int*    counts   = (int*)ws;  ws += (size_t)NBINS * sizeof(int);        // 13.1 MB
    int*    binstart = (int*)ws;  ws += ((size_t)NBINS + 16) * sizeof(int); // 13.1 MB
    int*    cursor   = (int*)ws;  ws += (size_t)NBINS * sizeof(int);        // 13.1 MB
    int*    sums     = (int*)ws;  ws += (size_t)SCAN_BLKS * sizeof(int);

    hipMemsetAsync(counts, 0, (size_t)NBINS * sizeof(int), stream);
    count_cells  <<<NTI*MI/256, 256, 0, stream>>>(traj, counts);
    scanA        <<<SCAN_BLKS,  256, 0, stream>>>(counts, binstart, sums);
    scanB        <<<1,          256, 0, stream>>>(sums);
    scanC        <<<SCAN_BLKS,  256, 0, stream>>>(binstart, sums, cursor);
    scatter_cells<<<NTI*MI/256, 256, 0, stream>>>(kr, ki, traj, dcf, cursor, recs);
    row_fft      <<<NTI*GI,     512, 0, stream>>>(binstart, recs, rowout);
    col_fft      <<<NTI*NCI*40, 512, 0, stream>>>(rowout, colimg);
    combine_kernel<<<dim3(NPIX/256, NTI), 256, 0, stream>>>(colimg, csr, csi, img);
    warp_sum     <<<NPIX/256,   256, 0, stream>>>(img, mot, out);
}

// Round 7
// 344.339 us; speedup vs baseline: 6.6710x; 1.2599x over previous
//
#include <hip/hip_runtime.h>
#include <math.h>

#define NXI 320
#define NCI 8
#define NTI 8
#define MI  65536
#define GI  640
#define G2I (GI*GI)
#define NPIX (NXI*NXI)
#define REC_F 20          // floats per record: {du,dv,0,0, 8x(re,im)}
#define SP 642            // padded LDS line stride (float2)
#define NBINS (NTI*G2I)   // 3,276,800 cells over all frames
#define SCAN_BLKS (NBINS/1024)   // 3200

__device__ inline float2 cmul(float2 a, float2 b) {
    return make_float2(a.x*b.x - a.y*b.y, a.x*b.y + a.y*b.x);
}
__device__ inline float2 cadd(float2 a, float2 b) { return make_float2(a.x+b.x, a.y+b.y); }
__device__ inline float2 csub(float2 a, float2 b) { return make_float2(a.x-b.x, a.y-b.y); }

__device__ inline float2 shfl_xor_c(float2 v, int m) {
    return make_float2(__shfl_xor(v.x, m, 64), __shfl_xor(v.y, m, 64));
}

__device__ inline void cell_of(const float* __restrict__ traj, int m, int f,
                               int& i0s, int& j0s, float& du, float& dv)
{
    float tu = traj[(m*2 + 0)*NTI + f];
    float tv = traj[(m*2 + 1)*NTI + f];
    float u = (tu + 0.5f) * (float)GI;
    float v = (tv + 0.5f) * (float)GI;
    float fu = floorf(u), fv = floorf(v);
    du = u - fu; dv = v - fv;
    i0s = (int)fu + GI/2; if (i0s >= GI) i0s -= GI;   // ifftshift folded in
    j0s = (int)fv + GI/2; if (j0s >= GI) j0s -= GI;
}

// ---------------- cell-level counting sort, all frames ----------------
__global__ __launch_bounds__(256) void count_cells(
    const float* __restrict__ traj, int* __restrict__ counts)
{
    int tid = blockIdx.x * 256 + threadIdx.x;   // f*MI + m
    int f = tid >> 16, m = tid & (MI - 1);
    int i0s, j0s; float du, dv;
    cell_of(traj, m, f, i0s, j0s, du, dv);
    atomicAdd(&counts[f*G2I + i0s*GI + j0s], 1);
}

__device__ inline int scan1024(int v, int tid, int* tmp) {
    tmp[tid] = v; __syncthreads();
    for (int d = 1; d < 1024; d <<= 1) {
        int y = (tid >= d) ? tmp[tid - d] : 0;
        __syncthreads();
        tmp[tid] += y;
        __syncthreads();
    }
    return tmp[tid];
}

__global__ __launch_bounds__(1024) void scanA(const int* __restrict__ counts,
                                              int* __restrict__ binstart,
                                              int* __restrict__ sums)
{
    __shared__ int tmp[1024];
    int tid = threadIdx.x;
    int i = blockIdx.x * 1024 + tid;
    int v = counts[i];
    int incl = scan1024(v, tid, tmp);
    binstart[i] = incl - v;                   // local exclusive
    if (tid == 1023) sums[blockIdx.x] = incl; // block total
}

// one block: exclusive scan of SCAN_BLKS block sums (chunk of 4 per thread)
__global__ __launch_bounds__(1024) void scanB(int* __restrict__ sums)
{
    __shared__ int tmp[1024];
    int tid = threadIdx.x;
    int base = tid * 4;
    int v[4]; int s = 0;
    #pragma unroll
    for (int q = 0; q < 4; ++q) {
        int idx = base + q;
        v[q] = (idx < SCAN_BLKS) ? sums[idx] : 0;
        s += v[q];
    }
    int incl = scan1024(s, tid, tmp);
    int run = incl - s;
    #pragma unroll
    for (int q = 0; q < 4; ++q) {
        int idx = base + q;
        if (idx < SCAN_BLKS) sums[idx] = run;
        run += v[q];
    }
}

__global__ __launch_bounds__(1024) void scanC(int* __restrict__ binstart,
                                              const int* __restrict__ sums,
                                              int* __restrict__ cursor)
{
    int i = blockIdx.x * 1024 + threadIdx.x;
    int v = binstart[i] + sums[blockIdx.x];
    binstart[i] = v;
    cursor[i] = v;
    if (i == NBINS - 1) binstart[NBINS] = NTI * MI;   // global sentinel
}

__global__ __launch_bounds__(256) void scatter_cells(
    const float* __restrict__ kr, const float* __restrict__ ki,
    const float* __restrict__ traj, const float* __restrict__ dcf,
    int* __restrict__ cursor, float* __restrict__ recs)
{
    int tid = blockIdx.x * 256 + threadIdx.x;   // f*MI + m
    int f = tid >> 16, m = tid & (MI - 1);
    int i0s, j0s; float du, dv;
    cell_of(traj, m, f, i0s, j0s, du, dv);
    float w = dcf[m*NTI + f];
    int slot = atomicAdd(&cursor[f*G2I + i0s*GI + j0s], 1);   // global slot
    float4* r = (float4*)(recs + (size_t)slot * REC_F);
    r[0] = make_float4(du, dv, 0.f, 0.f);
    #pragma unroll
    for (int q = 0; q < 4; ++q) {
        int c0 = 2*q;
        r[1+q] = make_float4(kr[c0*MI + m]*w,     ki[c0*MI + m]*w,
                             kr[(c0+1)*MI + m]*w, ki[(c0+1)*MI + m]*w);
    }
}

// ---------------- register-resident 640-pt iFFT (sign +) ----------------
__device__ inline void dft5p(float2 x0, float2 x1, float2 x2, float2 x3, float2 x4,
                             float2* X)   // X[u] = sum x[t] e^{+2pi i ut/5}
{
    const float c1 = 0.309016994f, c2 = -0.809016994f;
    const float s1 = 0.951056516f, s2 =  0.587785252f;
    float2 S1 = cadd(x1, x4), D1 = csub(x1, x4);
    float2 S2 = cadd(x2, x3), D2 = csub(x2, x3);
    X[0] = make_float2(x0.x + S1.x + S2.x, x0.y + S1.y + S2.y);
    float2 A = make_float2(x0.x + c1*S1.x + c2*S2.x, x0.y + c1*S1.y + c2*S2.y);
    float2 T = make_float2(s1*D1.x + s2*D2.x,        s1*D1.y + s2*D2.y);
    float2 B = make_float2(x0.x + c2*S1.x + c1*S2.x, x0.y + c2*S1.y + c1*S2.y);
    float2 U = make_float2(s2*D1.x - s1*D2.x,        s2*D1.y - s1*D2.y);
    X[1] = make_float2(A.x - T.y, A.y + T.x);
    X[4] = make_float2(A.x + T.y, A.y - T.x);
    X[2] = make_float2(B.x - U.y, B.y + U.x);
    X[3] = make_float2(B.x + U.y, B.y - U.x);
}

// T: LDS table of 64th roots, T[q] = e^{+2pi i q/64}
__device__ inline int fft640_reg(float2* a, int lane, float2* Z,
                                 const float2* __restrict__ T)
{
    const float PI = 3.14159265358979f;
    // 6 across-lane DIF stages; sign folded so high-lane twiddle = e^{+i pi lane/h}
    #pragma unroll
    for (int s = 0; s < 6; ++s) {
        const int h = 32 >> s;
        bool low = (lane & h) == 0;
        float2 wt = T[(lane << s) & 63];
        float2 w = low ? make_float2(1.f, 0.f) : wt;
        #pragma unroll
        for (int n = 0; n < 10; ++n) {
            float2 p = shfl_xor_c(a[n], h);
            float2 t = low ? cadd(p, a[n]) : csub(a[n], p);
            a[n] = cmul(t, w);
        }
    }
    int k1 = __brev(lane) >> 26;
    float th = (2.0f * PI / 640.0f) * (float)k1;
    float sn, cs;
    __sincosf(th, &sn, &cs);
    float2 wb = make_float2(cs, sn);
    float2 w = wb;
    #pragma unroll
    for (int n = 1; n < 10; ++n) {
        a[n] = cmul(a[n], w);
        w = cmul(w, wb);
    }
    float2 E[5], O[5];
    dft5p(a[0], a[2], a[4], a[6], a[8], E);
    dft5p(a[1], a[3], a[5], a[7], a[9], O);
    const float2 tk[5] = {{1.f, 0.f},
                          { 0.809016994f, 0.587785252f},
                          { 0.309016994f, 0.951056516f},
                          {-0.309016994f, 0.951056516f},
                          {-0.809016994f, 0.587785252f}};
    #pragma unroll
    for (int k = 0; k < 5; ++k) {
        float2 t = cmul(tk[k], O[k]);
        Z[k]     = cadd(E[k], t);
        Z[k + 5] = csub(E[k], t);
    }
    return k1;
}

__device__ inline void fill_T(float2* T, int tid, int nthr) {
    const float PI = 3.14159265358979f;
    for (int q = tid; q < 64; q += nthr) {
        float sn, cs;
        __sincosf((2.0f * PI / 64.0f) * q, &sn, &cs);
        T[q] = make_float2(cs, sn);
    }
}

// ---- fused atomic-free gather + row FFT: block = (frame, grid-row i) ----
__global__ __launch_bounds__(512) void row_fft(
    const int* __restrict__ binstart, const float* __restrict__ recs,
    float2* __restrict__ rowout)
{
    __shared__ float2 A[NCI][SP];
    __shared__ int boff[2][GI+1];
    __shared__ float2 T[64];
    int bid = blockIdx.x;               // f*GI + i
    int i = bid % GI;
    int f = bid / GI;
    int tid = threadIdx.x;
    fill_T(&T[0], tid, 512);
    int im1 = i ? i - 1 : GI - 1;
    const int base0 = f*G2I + i*GI;     // part 0: bin-row i   (row weight 1-du)
    const int base1 = f*G2I + im1*GI;   // part 1: bin-row i-1 (row weight du)
    for (int k = tid; k <= GI; k += 512) {
        boff[0][k] = binstart[base0 + k];
        boff[1][k] = binstart[base1 + k];
    }
    __syncthreads();

    // each thread owns output cell j for ALL 8 coils — header read once
    for (int j = tid; j < GI; j += 512) {
        int jm1 = j ? j - 1 : GI - 1;
        float2 acc[NCI];
        #pragma unroll
        for (int c = 0; c < NCI; ++c) acc[c] = make_float2(0.f, 0.f);
        #pragma unroll
        for (int p = 0; p < 2; ++p) {
            #pragma unroll
            for (int side = 0; side < 2; ++side) {
                int b = side ? jm1 : j;
                int s0 = boff[p][b], s1 = boff[p][b+1];
                for (int s = s0; s < s1; ++s) {
                    const float4* R = (const float4*)(recs + (size_t)s*REC_F);
                    float4 h4 = R[0];                 // du, dv
                    float wr = p ? h4.x : (1.f - h4.x);
                    float w  = wr * (side ? h4.y : (1.f - h4.y));
                    float4 d0 = R[1], d1 = R[2], d2 = R[3], d3 = R[4];
                    acc[0].x += w*d0.x; acc[0].y += w*d0.y;
                    acc[1].x += w*d0.z; acc[1].y += w*d0.w;
                    acc[2].x += w*d1.x; acc[2].y += w*d1.y;
                    acc[3].x += w*d1.z; acc[3].y += w*d1.w;
                    acc[4].x += w*d2.x; acc[4].y += w*d2.y;
                    acc[5].x += w*d2.z; acc[5].y += w*d2.w;
                    acc[6].x += w*d3.x; acc[6].y += w*d3.y;
                    acc[7].x += w*d3.z; acc[7].y += w*d3.w;
                }
            }
        }
        #pragma unroll
        for (int c = 0; c < NCI; ++c) A[c][j] = acc[c];
    }
    __syncthreads();

    int wv = tid >> 6, lane = tid & 63;   // wave wv owns coil wv
    float2 a[10];
    #pragma unroll
    for (int n = 0; n < 10; ++n) a[n] = A[wv][10*lane + n];
    float2 Z[10];
    int k1 = fft640_reg(a, lane, Z, &T[0]);
    #pragma unroll
    for (int k2 = 0; k2 < 10; ++k2) {
        int yc = k1 + 64*k2 + 160; if (yc >= GI) yc -= GI;
        A[wv][yc] = Z[k2];
    }
    // own-wave data only: no barrier needed
    float2* dst = rowout + (((size_t)f*NCI + wv)*GI + i)*NXI;
    #pragma unroll
    for (int q = 0; q < 5; ++q) {
        int yc = lane + 64*q;
        dst[yc] = A[wv][yc];
    }
}

// ---- col FFT + crop: block = (frame, coil, y-group of 8) ----
__global__ __launch_bounds__(512) void col_fft(
    const float2* __restrict__ rowout, float2* __restrict__ colimg)
{
    __shared__ float2 A[8][SP];
    __shared__ float2 T[64];
    int bid = blockIdx.x;               // (f*NCI + c)*40 + g
    int g = bid % 40;
    int c = (bid / 40) % NCI;
    int f = bid / (40*NCI);
    int y0 = g * 8;
    int tid = threadIdx.x;
    fill_T(&T[0], tid, 512);
    const float2* src = rowout + ((size_t)f*NCI + c)*GI*NXI + y0;
    for (int idx = tid; idx < 8*GI; idx += 512) {
        int l = idx & 7, k = idx >> 3;
        A[l][k] = src[(size_t)k*NXI + l];
    }
    __syncthreads();
    int wv = tid >> 6, lane = tid & 63;
    float2 a[10];
    #pragma unroll
    for (int n = 0; n < 10; ++n) a[n] = A[wv][10*lane + n];
    float2 Z[10];
    int k1 = fft640_reg(a, lane, Z, &T[0]);
    #pragma unroll
    for (int k2 = 0; k2 < 10; ++k2) {
        int xx = k1 + 64*k2 + 160; if (xx >= GI) xx -= GI;
        A[wv][xx] = Z[k2];
    }
    __syncthreads();
    float2* dst = colimg + ((size_t)f*NCI + c)*NPIX + y0;
    for (int idx = tid; idx < 8*NXI; idx += 512) {
        int l = idx & 7, xx = idx >> 3;
        dst[(size_t)xx*NXI + l] = A[l][xx];
    }
}

// ------------- deapodize + coil combine -------------
__global__ __launch_bounds__(256) void combine_kernel(
    const float2* __restrict__ colimg, const float* __restrict__ csr,
    const float* __restrict__ csi, float2* __restrict__ img)
{
    int f = blockIdx.y;
    int pix = blockIdx.x * 256 + threadIdx.x;
    int x = pix / NXI, y = pix - x*NXI;
    const float PI = 3.14159265358979f;
    float tx = (x - 160) * (1.0f/GI);
    float ty = (y - 160) * (1.0f/GI);
    float dx = 1.0f, dy = 1.0f;
    if (x != 160) { float s = __sinf(PI*tx) / (PI*tx); dx = s*s; }
    if (y != 160) { float s = __sinf(PI*ty) / (PI*ty); dy = s*s; }
    float scale = 1.0f / ((float)G2I * dx * dy);
    float accr = 0.f, acci = 0.f;
    #pragma unroll
    for (int c = 0; c < NCI; ++c) {
        float2 g = colimg[((size_t)f*NCI + c)*NPIX + pix];
        float cr = csr[c*NPIX + pix];
        float ci = csi[c*NPIX + pix];
        accr += cr*g.x + ci*g.y;
        acci += cr*g.y - ci*g.x;
    }
    img[(size_t)f*NPIX + pix] = make_float2(accr*scale, acci*scale);
}

// ---------------- warp all frames + sum ----------------
__global__ __launch_bounds__(256) void warp_sum(
    const float2* __restrict__ img, const float* __restrict__ motions,
    float* __restrict__ out)
{
    int pix = blockIdx.x * 256 + threadIdx.x;
    int x = pix / NXI, y = pix - x*NXI;
    float accr = 0.f, acci = 0.f;
    #pragma unroll
    for (int f = 0; f < NTI; ++f) {
        float fx = motions[(size_t)(pix*2 + 0)*NTI + f];
        float fy = motions[(size_t)(pix*2 + 1)*NTI + f];
        float xs = fminf(fmaxf((float)x + fx, 0.0f), (float)(NXI-1));
        float ys = fminf(fmaxf((float)y + fy, 0.0f), (float)(NXI-1));
        int x0 = (int)floorf(xs);
        int y0 = (int)floorf(ys);
        int x1 = min(x0+1, NXI-1);
        int y1 = min(y0+1, NXI-1);
        float dx = xs - (float)x0;
        float dy = ys - (float)y0;
        const float2* im = img + (size_t)f*NPIX;
        float2 v00 = im[x0*NXI + y0];
        float2 v10 = im[x1*NXI + y0];
        float2 v01 = im[x0*NXI + y1];
        float2 v11 = im[x1*NXI + y1];
        float w00 = (1.f-dx)*(1.f-dy), w10 = dx*(1.f-dy);
        float w01 = (1.f-dx)*dy,       w11 = dx*dy;
        accr += w00*v00.x + w10*v10.x + w01*v01.x + w11*v11.x;
        acci += w00*v00.y + w10*v10.y + w01*v01.y + w11*v11.y;
    }
    out[pix*2+0] = accr;
    out[pix*2+1] = acci;
}

extern "C" void kernel_launch(void* const* d_in, const int* in_sizes, int n_in,
                              void* d_out, int out_size, void* d_ws, size_t ws_size,
                              hipStream_t stream)
{
    const float* kr   = (const float*)d_in[0];
    const float* ki   = (const float*)d_in[1];
    const float* traj = (const float*)d_in[2];
    const float* csr  = (const float*)d_in[3];
    const float* csi  = (const float*)d_in[4];
    const float* dcf  = (const float*)d_in[5];
    const float* mot  = (const float*)d_in[6];
    float* out = (float*)d_out;

    char* ws = (char*)d_ws;
    float*  recs     = (float*)ws;                       // 41.94 MB
    ws += (size_t)NTI * MI * REC_F * sizeof(float);
    float2* rowout   = (float2*)ws;                      // 104.86 MB
    ws += (size_t)NTI * NCI * GI * NXI * sizeof(float2);
    float2* colimg   = (float2*)ws;                      // 52.43 MB
    ws += (size_t)NTI * NCI * NPIX * sizeof(float2);
    float2* img      = (float2*)ws;                      // 6.55 MB
    ws += (size_t)NTI * NPIX * sizeof(float2);
    int*    counts   = (int*)ws;  ws += (size_t)NBINS * sizeof(int);        // 13.1 MB
    int*    binstart = (int*)ws;  ws += ((size_t)NBINS + 16) * sizeof(int); // 13.1 MB
    int*    cursor   = (int*)ws;  ws += (size_t)NBINS * sizeof(int);        // 13.1 MB
    int*    sums     = (int*)ws;  ws += (size_t)SCAN_BLKS * sizeof(int);

    hipMemsetAsync(counts, 0, (size_t)NBINS * sizeof(int), stream);
    count_cells  <<<NTI*MI/256, 256, 0, stream>>>(traj, counts);
    scanA        <<<SCAN_BLKS, 1024, 0, stream>>>(counts, binstart, sums);
    scanB        <<<1,         1024, 0, stream>>>(sums);
    scanC        <<<SCAN_BLKS, 1024, 0, stream>>>(binstart, sums, cursor);
    scatter_cells<<<NTI*MI/256, 256, 0, stream>>>(kr, ki, traj, dcf, cursor, recs);
    row_fft      <<<NTI*GI,     512, 0, stream>>>(binstart, recs, rowout);
    col_fft      <<<NTI*NCI*40, 512, 0, stream>>>(rowout, colimg);
    combine_kernel<<<dim3(NPIX/256, NTI), 256, 0, stream>>>(colimg, csr, csi, img);
    warp_sum     <<<NPIX/256,   256, 0, stream>>>(img, mot, out);
}

// Round 8
// 306.862 us; speedup vs baseline: 7.4857x; 1.1221x over previous
//
#include <hip/hip_runtime.h>
#include <math.h>

#define NXI 320
#define NCI 8
#define NTI 8
#define MI  65536
#define GI  640
#define G2I (GI*GI)
#define NPIX (NXI*NXI)
#define REC_F 20          // floats per record: {du,dv,0,0, 8x(re,im)}
#define NBINS (NTI*G2I)   // 3,276,800 cells over all frames
#define SCAN_BLKS (NBINS/1024)   // 3200

typedef float v2f __attribute__((ext_vector_type(2)));

__device__ inline v2f cmul(v2f a, v2f b) {
    v2f axx = __builtin_shufflevector(a, a, 0, 0);
    v2f ayy = __builtin_shufflevector(a, a, 1, 1);
    v2f byx = __builtin_shufflevector(b, b, 1, 0);
    v2f r = axx * b;                  // (a.x b.x, a.x b.y)
    v2f t = ayy * byx;                // (a.y b.y, a.y b.x)
    return r + v2f{-t.x, t.y};
}

__device__ inline v2f shfl_xor_v(v2f v, int m) {
    return v2f{__shfl_xor(v.x, m, 64), __shfl_xor(v.y, m, 64)};
}

__device__ inline void cell_of(const float* __restrict__ traj, int m, int f,
                               int& i0s, int& j0s, float& du, float& dv)
{
    float tu = traj[(m*2 + 0)*NTI + f];
    float tv = traj[(m*2 + 1)*NTI + f];
    float u = (tu + 0.5f) * (float)GI;
    float v = (tv + 0.5f) * (float)GI;
    float fu = floorf(u), fv = floorf(v);
    du = u - fu; dv = v - fv;
    i0s = (int)fu + GI/2; if (i0s >= GI) i0s -= GI;   // ifftshift folded in
    j0s = (int)fv + GI/2; if (j0s >= GI) j0s -= GI;
}

// ---------------- cell-level counting sort, all frames ----------------
__global__ __launch_bounds__(256) void count_cells(
    const float* __restrict__ traj, int* __restrict__ counts)
{
    int tid = blockIdx.x * 256 + threadIdx.x;   // f*MI + m
    int f = tid >> 16, m = tid & (MI - 1);
    int i0s, j0s; float du, dv;
    cell_of(traj, m, f, i0s, j0s, du, dv);
    atomicAdd(&counts[f*G2I + i0s*GI + j0s], 1);
}

__device__ inline int scan1024(int v, int tid, int* tmp) {
    tmp[tid] = v; __syncthreads();
    for (int d = 1; d < 1024; d <<= 1) {
        int y = (tid >= d) ? tmp[tid - d] : 0;
        __syncthreads();
        tmp[tid] += y;
        __syncthreads();
    }
    return tmp[tid];
}

__global__ __launch_bounds__(1024) void scanA(const int* __restrict__ counts,
                                              int* __restrict__ binstart,
                                              int* __restrict__ sums)
{
    __shared__ int tmp[1024];
    int tid = threadIdx.x;
    int i = blockIdx.x * 1024 + tid;
    int v = counts[i];
    int incl = scan1024(v, tid, tmp);
    binstart[i] = incl - v;
    if (tid == 1023) sums[blockIdx.x] = incl;
}

__global__ __launch_bounds__(1024) void scanB(int* __restrict__ sums)
{
    __shared__ int tmp[1024];
    int tid = threadIdx.x;
    int base = tid * 4;
    int v[4]; int s = 0;
    #pragma unroll
    for (int q = 0; q < 4; ++q) {
        int idx = base + q;
        v[q] = (idx < SCAN_BLKS) ? sums[idx] : 0;
        s += v[q];
    }
    int incl = scan1024(s, tid, tmp);
    int run = incl - s;
    #pragma unroll
    for (int q = 0; q < 4; ++q) {
        int idx = base + q;
        if (idx < SCAN_BLKS) sums[idx] = run;
        run += v[q];
    }
}

__global__ __launch_bounds__(1024) void scanC(int* __restrict__ binstart,
                                              const int* __restrict__ sums,
                                              int* __restrict__ cursor)
{
    int i = blockIdx.x * 1024 + threadIdx.x;
    int v = binstart[i] + sums[blockIdx.x];
    binstart[i] = v;
    cursor[i] = v;
    if (i == NBINS - 1) binstart[NBINS] = NTI * MI;   // global sentinel
}

__global__ __launch_bounds__(256) void scatter_cells(
    const float* __restrict__ kr, const float* __restrict__ ki,
    const float* __restrict__ traj, const float* __restrict__ dcf,
    int* __restrict__ cursor, float* __restrict__ recs)
{
    int tid = blockIdx.x * 256 + threadIdx.x;   // f*MI + m
    int f = tid >> 16, m = tid & (MI - 1);
    int i0s, j0s; float du, dv;
    cell_of(traj, m, f, i0s, j0s, du, dv);
    float w = dcf[m*NTI + f];
    int slot = atomicAdd(&cursor[f*G2I + i0s*GI + j0s], 1);
    float4* r = (float4*)(recs + (size_t)slot * REC_F);
    r[0] = make_float4(du, dv, 0.f, 0.f);
    #pragma unroll
    for (int q = 0; q < 4; ++q) {
        int c0 = 2*q;
        r[1+q] = make_float4(kr[c0*MI + m]*w,     ki[c0*MI + m]*w,
                             kr[(c0+1)*MI + m]*w, ki[(c0+1)*MI + m]*w);
    }
}

// ---------------- register-resident 640-pt iFFT (sign +), packed ----------------
__device__ inline void dft5p(v2f x0, v2f x1, v2f x2, v2f x3, v2f x4, v2f* X)
{
    const float c1 = 0.309016994f, c2 = -0.809016994f;
    const float s1 = 0.951056516f, s2 =  0.587785252f;
    v2f S1 = x1 + x4, D1 = x1 - x4;
    v2f S2 = x2 + x3, D2 = x2 - x3;
    X[0] = x0 + S1 + S2;
    v2f A = x0 + c1*S1 + c2*S2;
    v2f T = s1*D1 + s2*D2;
    v2f B = x0 + c2*S1 + c1*S2;
    v2f U = s2*D1 - s1*D2;
    v2f iT = v2f{-T.y, T.x};
    v2f iU = v2f{-U.y, U.x};
    X[1] = A + iT;  X[4] = A - iT;
    X[2] = B + iU;  X[3] = B - iU;
}

// FFT 640 per wave (lane holds x[10*lane+n]); writes the 5 cropped outputs
// (yc = (j+160) mod 640 < 320) directly to LDS line with optional slot XOR.
__device__ inline void fft640_pruned(v2f* a, int lane, v2f* line, int xorm)
{
    const float PI = 3.14159265358979f;
    // 6 across-lane DIF stages; sign folded into twiddle index (lane<<s)&63
    #pragma unroll
    for (int s = 0; s < 6; ++s) {
        const int h = 32 >> s;
        bool low = (lane & h) == 0;
        int k = (lane << s) & 63;
        float sn, cs;
        __sincosf((2.0f * PI / 64.0f) * (float)k, &sn, &cs);
        v2f ws = v2f{cs, sn};
        #pragma unroll
        for (int n = 0; n < 10; ++n) {
            v2f p = shfl_xor_v(a[n], h);
            v2f tl = p + a[n];
            v2f th = cmul(a[n] - p, ws);
            a[n] = low ? tl : th;
        }
    }
    int k1 = __brev(lane) >> 26;
    float th2 = (2.0f * PI / 640.0f) * (float)k1;
    float sn, cs;
    __sincosf(th2, &sn, &cs);
    v2f wb = v2f{cs, sn};
    v2f w = wb;
    #pragma unroll
    for (int n = 1; n < 10; ++n) {
        a[n] = cmul(a[n], w);
        w = cmul(w, wb);
    }
    v2f E[5], O[5];
    dft5p(a[0], a[2], a[4], a[6], a[8], E);
    dft5p(a[1], a[3], a[5], a[7], a[9], O);
    const v2f tk1 = { 0.809016994f, 0.587785252f};
    const v2f tk2 = { 0.309016994f, 0.951056516f};
    const v2f tk3 = {-0.309016994f, 0.951056516f};
    const v2f tk4 = {-0.809016994f, 0.587785252f};
    v2f t1 = cmul(tk1, O[1]);
    v2f t2 = cmul(tk2, O[2]);
    v2f t3 = cmul(tk3, O[3]);
    v2f t4 = cmul(tk4, O[4]);
    bool hi = (k1 >= 32);
    line[(160 + k1) ^ xorm] = E[0] + O[0];          // k2=0
    line[(224 + k1) ^ xorm] = E[1] + t1;            // k2=1
    int yx = hi ? (k1 - 32) : (288 + k1);           // k2=7 : k2=2
    v2f zx = hi ? (E[2] - t2) : (E[2] + t2);
    line[yx ^ xorm] = zx;
    line[(32 + k1) ^ xorm] = E[3] - t3;             // k2=8
    line[(96 + k1) ^ xorm] = E[4] - t4;             // k2=9
}

// ---- fused atomic-free gather + row FFT: block = (frame, grid-row i) ----
__global__ __launch_bounds__(512, 8) void row_fft(
    const int* __restrict__ binstart, const float* __restrict__ recs,
    v2f* __restrict__ rowout)
{
    __shared__ v2f A[NCI][GI];      // 40,960 B exactly -> 4 blocks/CU
    int bid = blockIdx.x;           // f*GI + i
    int i = bid % GI;
    int f = bid / GI;
    int tid = threadIdx.x;
    int im1 = i ? i - 1 : GI - 1;
    const int* bsr[2] = { binstart + f*G2I + i*GI,      // p=0: row i   (1-du)
                          binstart + f*G2I + im1*GI };  // p=1: row i-1 (du)

    // thread owns output cell j for all 8 coils; bins j-1,j are contiguous
    for (int j = tid; j < GI; j += 512) {
        v2f acc[NCI];
        #pragma unroll
        for (int c = 0; c < NCI; ++c) acc[c] = v2f{0.f, 0.f};
        #pragma unroll
        for (int p = 0; p < 2; ++p) {
            const int* bs = bsr[p];
            if (j > 0) {
                int lo = bs[j-1], mid = bs[j], hi = bs[j+1];
                for (int s = lo; s < hi; ++s) {
                    const float4* R = (const float4*)(recs + (size_t)s*REC_F);
                    float4 h4 = R[0];
                    float wr = p ? h4.x : (1.f - h4.x);
                    float w  = wr * ((s < mid) ? h4.y : (1.f - h4.y));
                    float4 d0 = R[1], d1 = R[2], d2 = R[3], d3 = R[4];
                    acc[0] += w * v2f{d0.x, d0.y};  acc[1] += w * v2f{d0.z, d0.w};
                    acc[2] += w * v2f{d1.x, d1.y};  acc[3] += w * v2f{d1.z, d1.w};
                    acc[4] += w * v2f{d2.x, d2.y};  acc[5] += w * v2f{d2.z, d2.w};
                    acc[6] += w * v2f{d3.x, d3.y};  acc[7] += w * v2f{d3.z, d3.w};
                }
            } else {
                // j == 0: bin 639 (dv side) then bin 0 ((1-dv) side)
                #pragma unroll
                for (int side = 0; side < 2; ++side) {
                    int b = side ? 0 : (GI - 1);
                    int s0 = bs[b], s1 = bs[b+1];
                    for (int s = s0; s < s1; ++s) {
                        const float4* R = (const float4*)(recs + (size_t)s*REC_F);
                        float4 h4 = R[0];
                        float wr = p ? h4.x : (1.f - h4.x);
                        float w  = wr * (side ? (1.f - h4.y) : h4.y);
                        float4 d0 = R[1], d1 = R[2], d2 = R[3], d3 = R[4];
                        acc[0] += w * v2f{d0.x, d0.y};  acc[1] += w * v2f{d0.z, d0.w};
                        acc[2] += w * v2f{d1.x, d1.y};  acc[3] += w * v2f{d1.z, d1.w};
                        acc[4] += w * v2f{d2.x, d2.y};  acc[5] += w * v2f{d2.z, d2.w};
                        acc[6] += w * v2f{d3.x, d3.y};  acc[7] += w * v2f{d3.z, d3.w};
                    }
                }
            }
        }
        #pragma unroll
        for (int c = 0; c < NCI; ++c) A[c][j] = acc[c];
    }
    __syncthreads();

    int wv = tid >> 6, lane = tid & 63;   // wave wv owns coil wv
    v2f a[10];
    #pragma unroll
    for (int n = 0; n < 10; ++n) a[n] = A[wv][10*lane + n];
    fft640_pruned(a, lane, A[wv], 0);
    // own-wave data only: no barrier needed
    v2f* dst = rowout + (((size_t)f*NCI + wv)*GI + i)*NXI;
    #pragma unroll
    for (int q = 0; q < 5; ++q) {
        int yc = lane + 64*q;
        dst[yc] = A[wv][yc];
    }
}

// ---- col FFT + crop: block = (frame, coil, y-group of 8) ----
__global__ __launch_bounds__(512, 8) void col_fft(
    const v2f* __restrict__ rowout, v2f* __restrict__ colimg)
{
    __shared__ v2f A[8][GI];        // 40,960 B -> 4 blocks/CU
    int bid = blockIdx.x;           // (f*NCI + c)*40 + g
    int g = bid % 40;
    int c = (bid / 40) % NCI;
    int f = bid / (40*NCI);
    int y0 = g * 8;
    int tid = threadIdx.x;
    const v2f* src = rowout + ((size_t)f*NCI + c)*GI*NXI + y0;
    for (int idx = tid; idx < 8*GI; idx += 512) {
        int l = idx & 7, k = idx >> 3;
        A[l][k ^ (4*(l & 3))] = src[(size_t)k*NXI + l];   // XOR swizzle: kill 8-way write conflicts
    }
    __syncthreads();
    int wv = tid >> 6, lane = tid & 63;
    int xm = 4 * (wv & 3);
    v2f a[10];
    #pragma unroll
    for (int n = 0; n < 10; ++n) a[n] = A[wv][(10*lane + n) ^ xm];
    fft640_pruned(a, lane, A[wv], xm);
    __syncthreads();                // transpose write needs all waves
    v2f* dst = colimg + ((size_t)f*NCI + c)*NPIX + y0;
    for (int idx = tid; idx < 8*NXI; idx += 512) {
        int l = idx & 7, xx = idx >> 3;
        dst[(size_t)xx*NXI + l] = A[l][xx ^ (4*(l & 3))];
    }
}

// ------------- deapodize + coil combine -------------
__global__ __launch_bounds__(256) void combine_kernel(
    const float2* __restrict__ colimg, const float* __restrict__ csr,
    const float* __restrict__ csi, float2* __restrict__ img)
{
    int f = blockIdx.y;
    int pix = blockIdx.x * 256 + threadIdx.x;
    int x = pix / NXI, y = pix - x*NXI;
    const float PI = 3.14159265358979f;
    float tx = (x - 160) * (1.0f/GI);
    float ty = (y - 160) * (1.0f/GI);
    float dx = 1.0f, dy = 1.0f;
    if (x != 160) { float s = __sinf(PI*tx) / (PI*tx); dx = s*s; }
    if (y != 160) { float s = __sinf(PI*ty) / (PI*ty); dy = s*s; }
    float scale = 1.0f / ((float)G2I * dx * dy);
    float accr = 0.f, acci = 0.f;
    #pragma unroll
    for (int c = 0; c < NCI; ++c) {
        float2 g = colimg[((size_t)f*NCI + c)*NPIX + pix];
        float cr = csr[c*NPIX + pix];
        float ci = csi[c*NPIX + pix];
        accr += cr*g.x + ci*g.y;
        acci += cr*g.y - ci*g.x;
    }
    img[(size_t)f*NPIX + pix] = make_float2(accr*scale, acci*scale);
}

// ---------------- warp all frames + sum ----------------
__global__ __launch_bounds__(256) void warp_sum(
    const float2* __restrict__ img, const float* __restrict__ motions,
    float* __restrict__ out)
{
    int pix = blockIdx.x * 256 + threadIdx.x;
    int x = pix / NXI, y = pix - x*NXI;
    float accr = 0.f, acci = 0.f;
    #pragma unroll
    for (int f = 0; f < NTI; ++f) {
        float fx = motions[(size_t)(pix*2 + 0)*NTI + f];
        float fy = motions[(size_t)(pix*2 + 1)*NTI + f];
        float xs = fminf(fmaxf((float)x + fx, 0.0f), (float)(NXI-1));
        float ys = fminf(fmaxf((float)y + fy, 0.0f), (float)(NXI-1));
        int x0 = (int)floorf(xs);
        int y0 = (int)floorf(ys);
        int x1 = min(x0+1, NXI-1);
        int y1 = min(y0+1, NXI-1);
        float dx = xs - (float)x0;
        float dy = ys - (float)y0;
        const float2* im = img + (size_t)f*NPIX;
        float2 v00 = im[x0*NXI + y0];
        float2 v10 = im[x1*NXI + y0];
        float2 v01 = im[x0*NXI + y1];
        float2 v11 = im[x1*NXI + y1];
        float w00 = (1.f-dx)*(1.f-dy), w10 = dx*(1.f-dy);
        float w01 = (1.f-dx)*dy,       w11 = dx*dy;
        accr += w00*v00.x + w10*v10.x + w01*v01.x + w11*v11.x;
        acci += w00*v00.y + w10*v10.y + w01*v01.y + w11*v11.y;
    }
    out[pix*2+0] = accr;
    out[pix*2+1] = acci;
}

extern "C" void kernel_launch(void* const* d_in, const int* in_sizes, int n_in,
                              void* d_out, int out_size, void* d_ws, size_t ws_size,
                              hipStream_t stream)
{
    const float* kr   = (const float*)d_in[0];
    const float* ki   = (const float*)d_in[1];
    const float* traj = (const float*)d_in[2];
    const float* csr  = (const float*)d_in[3];
    const float* csi  = (const float*)d_in[4];
    const float* dcf  = (const float*)d_in[5];
    const float* mot  = (const float*)d_in[6];
    float* out = (float*)d_out;

    char* ws = (char*)d_ws;
    float*  recs     = (float*)ws;                       // 41.94 MB
    ws += (size_t)NTI * MI * REC_F * sizeof(float);
    v2f*    rowout   = (v2f*)ws;                         // 104.86 MB
    ws += (size_t)NTI * NCI * GI * NXI * sizeof(float2);
    float2* colimg   = (float2*)ws;                      // 52.43 MB
    ws += (size_t)NTI * NCI * NPIX * sizeof(float2);
    float2* img      = (float2*)ws;                      // 6.55 MB
    ws += (size_t)NTI * NPIX * sizeof(float2);
    int*    counts   = (int*)ws;  ws += (size_t)NBINS * sizeof(int);
    int*    binstart = (int*)ws;  ws += ((size_t)NBINS + 16) * sizeof(int);
    int*    cursor   = (int*)ws;  ws += (size_t)NBINS * sizeof(int);
    int*    sums     = (int*)ws;  ws += (size_t)SCAN_BLKS * sizeof(int);

    hipMemsetAsync(counts, 0, (size_t)NBINS * sizeof(int), stream);
    count_cells  <<<NTI*MI/256, 256, 0, stream>>>(traj, counts);
    scanA        <<<SCAN_BLKS, 1024, 0, stream>>>(counts, binstart, sums);
    scanB        <<<1,         1024, 0, stream>>>(sums);
    scanC        <<<SCAN_BLKS, 1024, 0, stream>>>(binstart, sums, cursor);
    scatter_cells<<<NTI*MI/256, 256, 0, stream>>>(kr, ki, traj, dcf, cursor, recs);
    row_fft      <<<NTI*GI,     512, 0, stream>>>(binstart, recs, rowout);
    col_fft      <<<NTI*NCI*40, 512, 0, stream>>>(rowout, (v2f*)colimg);
    combine_kernel<<<dim3(NPIX/256, NTI), 256, 0, stream>>>(colimg, csr, csi, img);
    warp_sum     <<<NPIX/256,   256, 0, stream>>>(img, mot, out);
}